// Round 17
// baseline (248.650 us; speedup 1.0000x reference)
//
#include <hip/hip_runtime.h>
#include <hip/hip_bf16.h>
#include <cstdint>
#include <cstddef>
#include <math.h>

#define D_ 1024
#define H_ 16
#define HD_ 64
#define T_ 2048
#define B_ 2
#define FF_ 4096
#define BT_ (B_*T_)   // 4096 rows
#define NT_ 32        // T_/64 kv tiles

typedef unsigned short u16;
typedef __attribute__((ext_vector_type(8))) __bf16 bf16x8;
typedef __attribute__((ext_vector_type(8))) u16 u16x8;
typedef __attribute__((ext_vector_type(4))) float f32x4;
typedef __attribute__((ext_vector_type(4))) unsigned u32x4;

__device__ __forceinline__ u16 f2bf(float f) {
  unsigned u = __builtin_bit_cast(unsigned, f);
  u += 0x7FFFu + ((u >> 16) & 1u);
  return (u16)(u >> 16);
}

__device__ __forceinline__ unsigned cvt_pk_bf16(float a, float b) {
  unsigned r;
  asm("v_cvt_pk_bf16_f32 %0, %1, %2" : "=v"(r) : "v"(a), "v"(b));
  return r;
}

__device__ __forceinline__ void gload16(const void* g, void* l) {
  __builtin_amdgcn_global_load_lds((__attribute__((address_space(1))) void*)g,
                                   (__attribute__((address_space(3))) void*)l, 16, 0, 0);
}

// ---------------- fused transpose + fp32->bf16 cast of ALL weights (1 launch)
__global__ __launch_bounds__(256) void transpose_all(
    const float* __restrict__ wq, const float* __restrict__ wk,
    const float* __restrict__ wv, const float* __restrict__ w_proj,
    const float* __restrict__ w1, const float* __restrict__ w2,
    u16* __restrict__ wqkv_t, u16* __restrict__ wproj_t,
    u16* __restrict__ w1t, u16* __restrict__ w2t) {
  __shared__ float tile[32][33];
  const int bid = blockIdx.x;
  const float* in; u16* out; int R, C, tx, ty;
  if (bid < 3072) {          // wq/wk/wv: [16][1024][64] each
    const int w = bid >> 10, rem = bid & 1023;
    const int z = rem >> 6, t = rem & 63;
    tx = t & 1; ty = t >> 1;
    R = D_; C = HD_;
    in  = (w == 0 ? wq : w == 1 ? wk : wv) + (size_t)z * R * C;
    out = wqkv_t + (size_t)w * D_ * D_ + (size_t)z * C * R;
  } else if (bid < 4096) {   // w_proj [1024][1024]
    const int t = bid - 3072;
    tx = t & 31; ty = t >> 5;
    R = D_; C = D_; in = w_proj; out = wproj_t;
  } else if (bid < 8192) {   // w1 [1024][4096]
    const int t = bid - 4096;
    tx = t & 127; ty = t >> 7;
    R = D_; C = FF_; in = w1; out = w1t;
  } else {                   // w2 [4096][1024]
    const int t = bid - 8192;
    tx = t & 31; ty = t >> 5;
    R = FF_; C = D_; in = w2; out = w2t;
  }
  const int x = tx * 32 + threadIdx.x;
  const int y0 = ty * 32 + threadIdx.y;
  #pragma unroll
  for (int j = 0; j < 32; j += 8)
    tile[threadIdx.y + j][threadIdx.x] = in[(size_t)(y0 + j) * C + x];
  __syncthreads();
  const int orr = ty * 32 + threadIdx.x;
  const int oc0 = tx * 32 + threadIdx.y;
  #pragma unroll
  for (int j = 0; j < 32; j += 8)
    out[(size_t)(oc0 + j) * R + orr] = f2bf(tile[threadIdx.x][threadIdx.y + j]);
}

// ---------------- LayerNorm (fp32 in -> bf16 out), one row (D=1024) per block of 256
__global__ __launch_bounds__(256) void ln_rows(const float* __restrict__ x,
    const float* __restrict__ g, const float* __restrict__ bb, u16* __restrict__ out) {
  const int row = blockIdx.x, tid = threadIdx.x;
  const float4 v = ((const float4*)(x + (size_t)row * D_))[tid];
  float s = v.x + v.y + v.z + v.w;
  float sq = v.x*v.x + v.y*v.y + v.z*v.z + v.w*v.w;
  #pragma unroll
  for (int m = 1; m < 64; m <<= 1) { s += __shfl_xor(s, m); sq += __shfl_xor(sq, m); }
  __shared__ float ss[4], qs[4];
  if ((tid & 63) == 0) { ss[tid >> 6] = s; qs[tid >> 6] = sq; }
  __syncthreads();
  s  = ss[0] + ss[1] + ss[2] + ss[3];
  sq = qs[0] + qs[1] + qs[2] + qs[3];
  const float mean = s * (1.f / D_);
  const float var  = sq * (1.f / D_) - mean * mean;
  const float rstd = rsqrtf(var + 1e-5f);
  const float4 gv = ((const float4*)g)[tid];
  const float4 bv = ((const float4*)bb)[tid];
  u16 o[4];
  o[0] = f2bf((v.x - mean) * rstd * gv.x + bv.x);
  o[1] = f2bf((v.y - mean) * rstd * gv.y + bv.y);
  o[2] = f2bf((v.z - mean) * rstd * gv.z + bv.z);
  o[3] = f2bf((v.w - mean) * rstd * gv.w + bv.w);
  *(ushort4*)(out + (size_t)row * D_ + tid * 4) = *(ushort4*)o;
}

// ---------------- GEMM 128x128, BK=32, 4 waves, 32KB LDS -> 4 blocks/CU,
// counted-vmcnt stage-ahead + T1 XCD swizzle + conflict-free chunk^row XOR layout.
// QKVE=1: epilogue writes the fused-QKV output directly in attention layout.
template<int ACT, int BIAS, int OUTBF, int PARTIAL, int QKVE>
__global__ __launch_bounds__(256, 4) void gemm128(
    const u16* __restrict__ A, const u16* __restrict__ Bt,
    const float* __restrict__ bias, const float* resid,
    void* Cout, int M, int N, int K, int Kper) {
  __shared__ __attribute__((aligned(16))) u16 LA[2][128 * 32];
  __shared__ __attribute__((aligned(16))) u16 LB[2][128 * 32];

  const int tid = threadIdx.x;
  const int wid = tid >> 6, lane = tid & 63;
  const int wr = wid >> 1, wc = wid & 1;       // wave -> 64x64 C block
  const int frow = lane & 15, hi = lane >> 4;

  const int gx = gridDim.x;
  const int nwg = gx * gridDim.y;
  const int orig = blockIdx.y * gx + blockIdx.x;
  const int cpx = nwg >> 3;
  const int swz = (orig & 7) * cpx + (orig >> 3);
  const int bm = (swz / gx) * 128, bn = (swz % gx) * 128;
  const int z = PARTIAL ? blockIdx.z : 0;
  const int koff = z * Kper;
  const int nt = Kper >> 5;

  const int srow = tid >> 2;
  const int gch  = (tid & 3) ^ (srow & 3);
  const u16* Ag0 = A + (size_t)(bm + srow) * K + koff + gch * 8;
  const u16* Ag1 = Ag0 + (size_t)64 * K;
  const u16* Bg0 = Bt + (size_t)(bn + srow) * K + koff + gch * 8;
  const u16* Bg1 = Bg0 + (size_t)64 * K;
  const int ldsA0 = (wid * 16) * 32, ldsA1 = (64 + wid * 16) * 32;

  f32x4 acc[4][4] = {};

  #define STAGE32(kt, db)                              \
    {                                                  \
      const int ko = (kt) * 32;                        \
      gload16(Ag0 + ko, &LA[db][ldsA0]);               \
      gload16(Ag1 + ko, &LA[db][ldsA1]);               \
      gload16(Bg0 + ko, &LB[db][ldsA0]);               \
      gload16(Bg1 + ko, &LB[db][ldsA1]);               \
    }

  STAGE32(0, 0);

  for (int t = 0; t < nt; ++t) {
    const int db = t & 1;
    if (t + 1 < nt) {
      STAGE32(t + 1, db ^ 1);
      asm volatile("s_waitcnt vmcnt(4)" ::: "memory");   // tile t landed; t+1 in flight
    } else {
      asm volatile("s_waitcnt vmcnt(0)" ::: "memory");
    }
    __builtin_amdgcn_s_barrier();

    const u16* Ab = &LA[db][0];
    const u16* Bb = &LB[db][0];

    bf16x8 af[4], bfr[4];
    #pragma unroll
    for (int i = 0; i < 4; i++) {
      const int ra = wr * 64 + i * 16 + frow;
      af[i]  = *(const bf16x8*)(Ab + ra * 32 + ((hi ^ (ra & 3)) << 3));
      const int rb = wc * 64 + i * 16 + frow;
      bfr[i] = *(const bf16x8*)(Bb + rb * 32 + ((hi ^ (rb & 3)) << 3));
    }
    __builtin_amdgcn_s_setprio(1);
    #pragma unroll
    for (int mi = 0; mi < 4; mi++)
      #pragma unroll
      for (int ni = 0; ni < 4; ni++)
        acc[mi][ni] = __builtin_amdgcn_mfma_f32_16x16x32_bf16(af[mi], bfr[ni], acc[mi][ni], 0, 0, 0);
    __builtin_amdgcn_s_setprio(0);
    __builtin_amdgcn_s_barrier();   // WAR: all waves done with buf db before restage
  }
  #undef STAGE32

  const int r0 = bm + wr * 64 + hi * 4;
  const int c0 = bn + wc * 64 + frow;
  #pragma unroll
  for (int mi = 0; mi < 4; mi++) {
    #pragma unroll
    for (int ni = 0; ni < 4; ni++) {
      #pragma unroll
      for (int r = 0; r < 4; r++) {
        float v = acc[mi][ni][r];
        const int rr = r0 + mi * 16 + r;
        const int cc = c0 + ni * 16;
        if (QKVE) {
          const int region = bn >> 10;            // 0=Q, 1=K, 2=V
          u16* qo = (u16*)Cout;
          u16* ko = qo + (size_t)4 * 1024 * 1024; // +8MB
          u16* vo = qo + (size_t)8 * 1024 * 1024; // +16MB
          const int c1 = cc & 1023;
          const int h = c1 >> 6, d = c1 & 63;
          const int bb2 = rr >> 11, t2 = rr & 2047;
          const int bh = bb2 * 16 + h;
          if (region == 0)
            qo[((size_t)bh * T_ + t2) * HD_ + d] = f2bf(v * 0.18033688011112042f);
          else if (region == 1)
            ko[((size_t)bh * T_ + t2) * HD_ + d] = f2bf(v);
          else
            vo[((size_t)bh * HD_ + d) * T_ + t2] = f2bf(v);
        } else if (PARTIAL) {
          ((float*)Cout)[((size_t)z * M + rr) * N + cc] = v;
        } else {
          if (BIAS) v += bias[cc];
          if (ACT == 1) {
            const float u = v * (0.79788456f + 0.03567740814f * v * v);
            const float e = exp2f(fminf(u * 2.885390082f, 80.f));
            v = v - v * __builtin_amdgcn_rcpf(1.0f + e);
          }
          if (resid) v += resid[(size_t)rr * N + cc];
          if (OUTBF) ((u16*)Cout)[(size_t)rr * N + cc] = f2bf(v);
          else       ((float*)Cout)[(size_t)rr * N + cc] = v;
        }
      }
    }
  }
}

// ---------------- split-K reduce: out = sum(parts) + bias (+resid), fp32
template<int NPART>
__global__ __launch_bounds__(256) void reduce_parts(
    const float* __restrict__ parts, const float* __restrict__ bias,
    const float* __restrict__ resid, float* __restrict__ out, int MN, int N) {
  const int i4 = (blockIdx.x * 256 + threadIdx.x) * 4;
  if (i4 >= MN) return;
  float4 s = *(const float4*)(parts + i4);
  #pragma unroll
  for (int p = 1; p < NPART; p++) {
    const float4 t = *(const float4*)(parts + (size_t)p * MN + i4);
    s.x += t.x; s.y += t.y; s.z += t.z; s.w += t.w;
  }
  const float4 bv = *(const float4*)(bias + (i4 & (N - 1)));
  const float4 rv = *(const float4*)(resid + i4);
  s.x += bv.x + rv.x; s.y += bv.y + rv.y; s.z += bv.z + rv.z; s.w += bv.w + rv.w;
  *(float4*)(out + i4) = s;
}

// ---------------- proj reduce (NPART=2) + bias + residual + LN2 fused.
__global__ __launch_bounds__(256) void reduce2_ln(
    const float* __restrict__ parts, const float* __restrict__ bias,
    const float* __restrict__ resid, const float* __restrict__ g,
    const float* __restrict__ bb, float* __restrict__ xout,
    u16* __restrict__ h2, int MN) {
  const int row = blockIdx.x, tid = threadIdx.x;
  const int i4 = row * D_ + tid * 4;
  float4 s = *(const float4*)(parts + i4);
  const float4 t = *(const float4*)(parts + (size_t)MN + i4);
  const float4 bv = *(const float4*)(bias + tid * 4);
  const float4 rv = *(const float4*)(resid + i4);
  s.x += t.x + bv.x + rv.x; s.y += t.y + bv.y + rv.y;
  s.z += t.z + bv.z + rv.z; s.w += t.w + bv.w + rv.w;
  *(float4*)(xout + i4) = s;
  float sm = s.x + s.y + s.z + s.w;
  float sq = s.x*s.x + s.y*s.y + s.z*s.z + s.w*s.w;
  #pragma unroll
  for (int m = 1; m < 64; m <<= 1) { sm += __shfl_xor(sm, m); sq += __shfl_xor(sq, m); }
  __shared__ float ss[4], qs[4];
  if ((tid & 63) == 0) { ss[tid >> 6] = sm; qs[tid >> 6] = sq; }
  __syncthreads();
  sm = ss[0] + ss[1] + ss[2] + ss[3];
  sq = qs[0] + qs[1] + qs[2] + qs[3];
  const float mean = sm * (1.f / D_);
  const float var  = sq * (1.f / D_) - mean * mean;
  const float rstd = rsqrtf(var + 1e-5f);
  const float4 gv = ((const float4*)g)[tid];
  const float4 b2v = ((const float4*)bb)[tid];
  u16 o[4];
  o[0] = f2bf((s.x - mean) * rstd * gv.x + b2v.x);
  o[1] = f2bf((s.y - mean) * rstd * gv.y + b2v.y);
  o[2] = f2bf((s.z - mean) * rstd * gv.z + b2v.z);
  o[3] = f2bf((s.w - mean) * rstd * gv.w + b2v.w);
  *(ushort4*)(h2 + (size_t)row * D_ + tid * 4) = *(ushort4*)o;
}

// ---------------- flash attention v8b: swapped-operand QK^T (S^T = K*Q^T), softmax
// fully in-register; P->A-frag via cvt_pk + DEST-SELECTED dual shfl (round-16 bugfix:
// __shfl evaluates the operand on the SOURCE lane, so bank selection must happen on
// the destination after both banks are shuffled). 4-wave blocks, QBLK=64, paired
// q-blocks (qb, 31-qb) -> 512 uniform blocks; XCD-bh L2 locality; defer-max THR=8.
__global__ __launch_bounds__(256, 2) void attn_fwd(
    const u16* __restrict__ q, const u16* __restrict__ k,
    const u16* __restrict__ vt, u16* __restrict__ out) {
  __shared__ __attribute__((aligned(16))) u16 Kb[2][64 * 64];   // 16KB
  __shared__ __attribute__((aligned(16))) u16 Vb[2][64 * 64];   // 16KB

  const int bid = blockIdx.x;                // 512 blocks
  const int xcd = bid & 7, j = bid >> 3;     // j = 0..63
  const int bh  = xcd + 8 * (j & 3);         // 4 bh per xcd -> 2MB K/V, L2-resident
  const int qp  = j >> 2;                    // 0..15 -> q-blocks {qp, 31-qp}
  const int b = bh >> 4, h = bh & 15;
  const int tid = threadIdx.x, wid = tid >> 6, lane = tid & 63;
  const u16* kh = k  + (size_t)bh * T_ * HD_;
  const u16* vh = vt + (size_t)bh * HD_ * T_;

  const int frow = lane & 15;                // this lane's q-row (within wave's 16)
  const int hi   = lane >> 4;                // k-subgroup 0..3
  const int fk   = hi * 8;
  const int rowb = hi * 4;
  const int srow = tid >> 3;                 // staging row 0..31 (per 32-row pass)
  const int gch  = (tid & 7) ^ (srow & 7);   // pre-swizzled chunk

  for (int qi = 0; qi < 2; ++qi) {
    const int qb = qi ? (31 - qp) : qp;      // q-block of 64 rows
    const int q0 = qb * 64;
    const int nkt = qb + 1;

    // Q in regs: B-operand of swapped QK^T (lane holds Q[q=frow][d-chunk hi])
    const u16* qrow = q + ((size_t)bh * T_ + q0 + wid * 16 + frow) * HD_;
    bf16x8 aq[2];
    aq[0] = *(const bf16x8*)(qrow + fk);
    aq[1] = *(const bf16x8*)(qrow + 32 + fk);

    float m2 = -3e38f;       // running max (log2 domain) for q=frow
    float acc_l = 0.f;       // partial denom (this lane's k-slice) for q=frow
    f32x4 acc_o[4] = {};     // O[q=rowb+r][d=ni*16+frow]

    int cur = 0;
    #pragma unroll
    for (int p = 0; p < 2; p++) {
      gload16(kh + (size_t)(p * 32 + srow) * HD_ + gch * 8, &Kb[0][(p * 32 + wid * 8) * 64]);
      gload16(vh + (size_t)(p * 32 + srow) * T_ + gch * 8,  &Vb[0][(p * 32 + wid * 8) * 64]);
    }
    __syncthreads();

    for (int kt = 0; kt < nkt; ++kt) {
      if (kt + 1 < nkt) {
        const int nx = cur ^ 1, ktn = kt + 1;
        #pragma unroll
        for (int p = 0; p < 2; p++) {
          gload16(kh + (size_t)(ktn * 64 + p * 32 + srow) * HD_ + gch * 8,
                  &Kb[nx][(p * 32 + wid * 8) * 64]);
          gload16(vh + (size_t)(p * 32 + srow) * T_ + ktn * 64 + gch * 8,
                  &Vb[nx][(p * 32 + wid * 8) * 64]);
        }
      }

      const u16* Kc = &Kb[cur][0];
      const u16* Vc = &Vb[cur][0];

      // ---- swapped QK^T: S^T[k][q] = mfma(A=K, B=Q). Lane holds
      // p2[ni][r] = S^T[k = ni*16+rowb+r][q = frow]  (q pre-scaled by 0.125*log2e)
      f32x4 p2[4];
      __builtin_amdgcn_s_setprio(1);
      #pragma unroll
      for (int ni = 0; ni < 4; ni++) {
        f32x4 s = {};
        #pragma unroll
        for (int ks = 0; ks < 2; ks++) {
          const int row = ni * 16 + frow;
          const int ch  = ks * 4 + hi;
          bf16x8 bk = *(const bf16x8*)(Kc + row * 64 + ((ch ^ (row & 7)) << 3));
          s = __builtin_amdgcn_mfma_f32_16x16x32_bf16(bk, aq[ks], s, 0, 0, 0);
        }
        p2[ni] = s;
      }
      __builtin_amdgcn_s_setprio(0);

      if (kt == nkt - 1) {  // diagonal tile: mask k > q (within-tile indices)
        #pragma unroll
        for (int ni = 0; ni < 4; ni++)
          #pragma unroll
          for (int r = 0; r < 4; r++)
            if ((ni * 16 + rowb + r) > (wid * 16 + frow)) p2[ni][r] = -3e38f;
      }

      // ---- lazy max (register-local 16 values; cross-lane only on rescale)
      float lm = fmaxf(fmaxf(p2[0][0], p2[0][1]), fmaxf(p2[0][2], p2[0][3]));
      #pragma unroll
      for (int ni = 1; ni < 4; ni++)
        lm = fmaxf(lm, fmaxf(fmaxf(p2[ni][0], p2[ni][1]), fmaxf(p2[ni][2], p2[ni][3])));
      if (!__all(lm <= m2 + 8.0f)) {
        float rm = lm;
        rm = fmaxf(rm, __shfl_xor(rm, 16));
        rm = fmaxf(rm, __shfl_xor(rm, 32));
        const float mnew = fmaxf(m2, rm);
        const float corr = exp2f(m2 - mnew);
        m2 = mnew;
        acc_l *= corr;
        #pragma unroll
        for (int r = 0; r < 4; r++) {
          const float cr = __shfl(corr, (lane & 48) | (rowb + r));
          #pragma unroll
          for (int ni = 0; ni < 4; ni++) acc_o[ni][r] *= cr;
        }
      }
      float ls = 0.f;
      #pragma unroll
      for (int ni = 0; ni < 4; ni++)
        #pragma unroll
        for (int r = 0; r < 4; r++) {
          const float e = exp2f(p2[ni][r] - m2);
          p2[ni][r] = e;
          ls += e;
        }
      acc_l += ls;

      // ---- P (S^T layout) -> A-frag. pk[ni][pr] packs k = ni*16+rowb+2pr (+1).
      // Target word w of half ks needs k = ks*32+8*hi+2w (+1) from source lane
      // (lane&15)|(hi_s<<4), hi_s = ((hi&1)<<1)|(w>>1), bank ni = 2ks+(hi>>1),
      // word pr = w&1. BUGFIX: shuffle BOTH banks, select by dest's hi afterwards.
      unsigned pk[4][2];
      #pragma unroll
      for (int ni = 0; ni < 4; ni++) {
        pk[ni][0] = cvt_pk_bf16(p2[ni][0], p2[ni][1]);
        pk[ni][1] = cvt_pk_bf16(p2[ni][2], p2[ni][3]);
      }
      bf16x8 ap[2];
      #pragma unroll
      for (int ks = 0; ks < 2; ks++) {
        u32x4 wv4;
        #pragma unroll
        for (int w = 0; w < 4; w++) {
          const int hi_s = ((hi & 1) << 1) | (w >> 1);
          const int srcl = (lane & 15) | (hi_s << 4);
          const unsigned lo = (unsigned)__shfl((int)pk[2 * ks][w & 1], srcl);
          const unsigned hi2 = (unsigned)__shfl((int)pk[2 * ks + 1][w & 1], srcl);
          wv4[w] = (hi & 2) ? hi2 : lo;
        }
        ap[ks] = __builtin_bit_cast(bf16x8, wv4);
      }

      // ---- PV: O += P*V (A=ap has q on row axis; B=V^T rows from LDS)
      __builtin_amdgcn_s_setprio(1);
      #pragma unroll
      for (int ni = 0; ni < 4; ni++) {
        #pragma unroll
        for (int ks = 0; ks < 2; ks++) {
          const int row = ni * 16 + frow;
          const int ch  = ks * 4 + hi;
          bf16x8 bv = *(const bf16x8*)(Vc + row * 64 + ((ch ^ (row & 7)) << 3));
          acc_o[ni] = __builtin_amdgcn_mfma_f32_16x16x32_bf16(ap[ks], bv, acc_o[ni], 0, 0, 0);
        }
      }
      __builtin_amdgcn_s_setprio(0);

      __syncthreads();
      cur ^= 1;
    }

    // ---- epilogue: combine l across the 4 lanes of each q-row, normalize, write
    acc_l += __shfl_xor(acc_l, 16);
    acc_l += __shfl_xor(acc_l, 32);
    const float linv_q = 1.0f / acc_l;          // for q = frow
    #pragma unroll
    for (int r = 0; r < 4; r++) {
      const float lr = __shfl(linv_q, (lane & 48) | (rowb + r));
      #pragma unroll
      for (int ni = 0; ni < 4; ni++) {
        const float ov = acc_o[ni][r] * lr;
        const size_t row = (size_t)b * T_ + q0 + wid * 16 + rowb + r;
        out[row * D_ + h * HD_ + ni * 16 + frow] = f2bf(ov);
      }
    }
  }
}

extern "C" void kernel_launch(void* const* d_in, const int* in_sizes, int n_in,
                              void* d_out, int out_size, void* d_ws, size_t ws_size,
                              hipStream_t stream) {
  (void)in_sizes; (void)n_in; (void)out_size; (void)ws_size;
  const float* x      = (const float*)d_in[0];
  const float* wq     = (const float*)d_in[1];
  const float* wk     = (const float*)d_in[2];
  const float* wv     = (const float*)d_in[3];
  const float* w_proj = (const float*)d_in[4];
  const float* b_proj = (const float*)d_in[5];
  const float* ln1_g  = (const float*)d_in[6];
  const float* ln1_b  = (const float*)d_in[7];
  const float* ln2_g  = (const float*)d_in[8];
  const float* ln2_b  = (const float*)d_in[9];
  const float* w1     = (const float*)d_in[10];
  const float* b1     = (const float*)d_in[11];
  const float* w2     = (const float*)d_in[12];
  const float* b2     = (const float*)d_in[13];

  uint8_t* ws = (uint8_t*)d_ws;
  const size_t MB = 1024 * 1024;
  u16* wqkv_t = (u16*)(ws + 0);        // [3072,1024]
  u16* wproj_t = (u16*)(ws + 6 * MB);  // [1024,1024]
  u16* w1t  = (u16*)(ws + 8 * MB);     // [4096,1024]
  u16* w2t  = (u16*)(ws + 16 * MB);    // [1024,4096]
  u16* hbuf = (u16*)(ws + 24 * MB);    // [4096,1024]
  u16* qb   = (u16*)(ws + 56 * MB);    // [32,2048,64]  Q (scaled)
  u16* kb   = (u16*)(ws + 64 * MB);    // [32,2048,64]  K   (qb+8MB)
  u16* vtb  = (u16*)(ws + 72 * MB);    // [32,64,2048]  V^T (qb+16MB)
  u16* aout = (u16*)(ws + 80 * MB);    // [4096,1024]
  u16* h2   = (u16*)(ws + 88 * MB);    // [4096,1024]
  u16* ff1  = (u16*)(ws + 96 * MB);    // [4096,4096]
  float* pparts = (float*)(ws + 32 * MB);  // proj: 2 x [4096,1024] fp32 = 32 MB
  float* fparts = (float*)(ws + 32 * MB);  // ff2:  4 x [4096,1024] fp32 = 64 MB
  float* xout = (float*)d_out;

  transpose_all<<<12288, dim3(32, 8), 0, stream>>>(
      wq, wk, wv, w_proj, w1, w2, wqkv_t, wproj_t, w1t, w2t);

  ln_rows<<<BT_, 256, 0, stream>>>(x, ln1_g, ln1_b, hbuf);

  // QKV GEMM with fused repack epilogue: writes q(scaled)/k/vt directly
  gemm128<0,0,0,0,1><<<dim3(3072/128, BT_/128), 256, 0, stream>>>(
      hbuf, wqkv_t, nullptr, nullptr, qb, BT_, 3072, D_, D_);

  attn_fwd<<<dim3(512), 256, 0, stream>>>(qb, kb, vtb, aout);

  // proj: split-K=2 partials, then fused reduce + bias + x-residual + LN2
  gemm128<0,0,0,1,0><<<dim3(D_/128, BT_/128, 2), 256, 0, stream>>>(
      aout, wproj_t, nullptr, nullptr, pparts, BT_, D_, D_, D_/2);
  reduce2_ln<<<BT_, 256, 0, stream>>>(
      pparts, b_proj, x, ln2_g, ln2_b, xout, h2, BT_*D_);

  // FF1: [4096,1024] x [4096,1024]^T -> GELU -> bf16 [4096,4096]
  gemm128<1,1,1,0,0><<<dim3(FF_/128, BT_/128), 256, 0, stream>>>(
      h2, w1t, b1, nullptr, ff1, BT_, FF_, D_, D_);

  // FF2: split-K=4 partials + fused reduce (bias + xout residual) -> xout in place
  gemm128<0,0,0,1,0><<<dim3(D_/128, BT_/128, 4), 256, 0, stream>>>(
      ff1, w2t, nullptr, nullptr, fparts, BT_, D_, FF_, FF_/4);
  reduce_parts<4><<<(BT_*D_)/1024, 256, 0, stream>>>(
      fparts, b2, xout, xout, BT_*D_, D_);
}

// Round 18
// 243.482 us; speedup vs baseline: 1.0212x; 1.0212x over previous
//
#include <hip/hip_runtime.h>
#include <hip/hip_bf16.h>
#include <cstdint>
#include <cstddef>
#include <math.h>

#define D_ 1024
#define H_ 16
#define HD_ 64
#define T_ 2048
#define B_ 2
#define FF_ 4096
#define BT_ (B_*T_)   // 4096 rows
#define NT_ 32        // T_/64 kv tiles

typedef unsigned short u16;
typedef __attribute__((ext_vector_type(8))) __bf16 bf16x8;
typedef __attribute__((ext_vector_type(8))) u16 u16x8;
typedef __attribute__((ext_vector_type(4))) float f32x4;

__device__ __forceinline__ u16 f2bf(float f) {
  unsigned u = __builtin_bit_cast(unsigned, f);
  u += 0x7FFFu + ((u >> 16) & 1u);
  return (u16)(u >> 16);
}

__device__ __forceinline__ unsigned cvt_pk_bf16(float a, float b) {
  unsigned r;
  asm("v_cvt_pk_bf16_f32 %0, %1, %2" : "=v"(r) : "v"(a), "v"(b));
  return r;
}

__device__ __forceinline__ void gload16(const void* g, void* l) {
  __builtin_amdgcn_global_load_lds((__attribute__((address_space(1))) void*)g,
                                   (__attribute__((address_space(3))) void*)l, 16, 0, 0);
}

// ---------------- fused prep: transpose+cast ALL weights AND LayerNorm1 (1 launch)
// blocks 0..12287: weight transpose tiles; blocks 12288..16383: LN1 rows.
__global__ __launch_bounds__(256) void prep_all(
    const float* __restrict__ wq, const float* __restrict__ wk,
    const float* __restrict__ wv, const float* __restrict__ w_proj,
    const float* __restrict__ w1, const float* __restrict__ w2,
    u16* __restrict__ wqkv_t, u16* __restrict__ wproj_t,
    u16* __restrict__ w1t, u16* __restrict__ w2t,
    const float* __restrict__ x, const float* __restrict__ ln1_g,
    const float* __restrict__ ln1_b, u16* __restrict__ hbuf) {
  __shared__ float tile[32][33];
  __shared__ float ss[4], qs[4];
  const int bid = blockIdx.x;
  if (bid >= 12288) {
    // ---- LayerNorm path (fp32 x -> bf16 hbuf), one row per block
    const int row = bid - 12288;
    const int tid = threadIdx.y * 32 + threadIdx.x;
    const float4 v = ((const float4*)(x + (size_t)row * D_))[tid];
    float s = v.x + v.y + v.z + v.w;
    float sq = v.x*v.x + v.y*v.y + v.z*v.z + v.w*v.w;
    #pragma unroll
    for (int m = 1; m < 64; m <<= 1) { s += __shfl_xor(s, m); sq += __shfl_xor(sq, m); }
    if ((tid & 63) == 0) { ss[tid >> 6] = s; qs[tid >> 6] = sq; }
    __syncthreads();
    s  = ss[0] + ss[1] + ss[2] + ss[3];
    sq = qs[0] + qs[1] + qs[2] + qs[3];
    const float mean = s * (1.f / D_);
    const float var  = sq * (1.f / D_) - mean * mean;
    const float rstd = rsqrtf(var + 1e-5f);
    const float4 gv = ((const float4*)ln1_g)[tid];
    const float4 bv = ((const float4*)ln1_b)[tid];
    u16 o[4];
    o[0] = f2bf((v.x - mean) * rstd * gv.x + bv.x);
    o[1] = f2bf((v.y - mean) * rstd * gv.y + bv.y);
    o[2] = f2bf((v.z - mean) * rstd * gv.z + bv.z);
    o[3] = f2bf((v.w - mean) * rstd * gv.w + bv.w);
    *(ushort4*)(hbuf + (size_t)row * D_ + tid * 4) = *(ushort4*)o;
    return;
  }
  // ---- weight transpose path
  const float* in; u16* out; int R, C, tx, ty;
  if (bid < 3072) {          // wq/wk/wv: [16][1024][64] each
    const int w = bid >> 10, rem = bid & 1023;
    const int z = rem >> 6, t = rem & 63;
    tx = t & 1; ty = t >> 1;
    R = D_; C = HD_;
    in  = (w == 0 ? wq : w == 1 ? wk : wv) + (size_t)z * R * C;
    out = wqkv_t + (size_t)w * D_ * D_ + (size_t)z * C * R;
  } else if (bid < 4096) {   // w_proj [1024][1024]
    const int t = bid - 3072;
    tx = t & 31; ty = t >> 5;
    R = D_; C = D_; in = w_proj; out = wproj_t;
  } else if (bid < 8192) {   // w1 [1024][4096]
    const int t = bid - 4096;
    tx = t & 127; ty = t >> 7;
    R = D_; C = FF_; in = w1; out = w1t;
  } else {                   // w2 [4096][1024]
    const int t = bid - 8192;
    tx = t & 31; ty = t >> 5;
    R = FF_; C = D_; in = w2; out = w2t;
  }
  const int xx = tx * 32 + threadIdx.x;
  const int y0 = ty * 32 + threadIdx.y;
  #pragma unroll
  for (int j = 0; j < 32; j += 8)
    tile[threadIdx.y + j][threadIdx.x] = in[(size_t)(y0 + j) * C + xx];
  __syncthreads();
  const int orr = ty * 32 + threadIdx.x;
  const int oc0 = tx * 32 + threadIdx.y;
  #pragma unroll
  for (int j = 0; j < 32; j += 8)
    out[(size_t)(oc0 + j) * R + orr] = f2bf(tile[threadIdx.x][threadIdx.y + j]);
}

// ---------------- GEMM 128x128, BK=32, 4 waves, 32KB LDS -> 4 blocks/CU,
// counted-vmcnt stage-ahead + T1 XCD swizzle + conflict-free chunk^row XOR layout.
// QKVE=1: epilogue writes the fused-QKV output directly in attention layout.
template<int ACT, int BIAS, int OUTBF, int PARTIAL, int QKVE>
__global__ __launch_bounds__(256, 4) void gemm128(
    const u16* __restrict__ A, const u16* __restrict__ Bt,
    const float* __restrict__ bias, const float* resid,
    void* Cout, int M, int N, int K, int Kper) {
  __shared__ __attribute__((aligned(16))) u16 LA[2][128 * 32];
  __shared__ __attribute__((aligned(16))) u16 LB[2][128 * 32];

  const int tid = threadIdx.x;
  const int wid = tid >> 6, lane = tid & 63;
  const int wr = wid >> 1, wc = wid & 1;       // wave -> 64x64 C block
  const int frow = lane & 15, hi = lane >> 4;

  const int gx = gridDim.x;
  const int nwg = gx * gridDim.y;
  const int orig = blockIdx.y * gx + blockIdx.x;
  const int cpx = nwg >> 3;
  const int swz = (orig & 7) * cpx + (orig >> 3);
  const int bm = (swz / gx) * 128, bn = (swz % gx) * 128;
  const int z = PARTIAL ? blockIdx.z : 0;
  const int koff = z * Kper;
  const int nt = Kper >> 5;

  const int srow = tid >> 2;
  const int gch  = (tid & 3) ^ (srow & 3);
  const u16* Ag0 = A + (size_t)(bm + srow) * K + koff + gch * 8;
  const u16* Ag1 = Ag0 + (size_t)64 * K;
  const u16* Bg0 = Bt + (size_t)(bn + srow) * K + koff + gch * 8;
  const u16* Bg1 = Bg0 + (size_t)64 * K;
  const int ldsA0 = (wid * 16) * 32, ldsA1 = (64 + wid * 16) * 32;

  f32x4 acc[4][4] = {};

  #define STAGE32(kt, db)                              \
    {                                                  \
      const int ko = (kt) * 32;                        \
      gload16(Ag0 + ko, &LA[db][ldsA0]);               \
      gload16(Ag1 + ko, &LA[db][ldsA1]);               \
      gload16(Bg0 + ko, &LB[db][ldsA0]);               \
      gload16(Bg1 + ko, &LB[db][ldsA1]);               \
    }

  STAGE32(0, 0);

  for (int t = 0; t < nt; ++t) {
    const int db = t & 1;
    if (t + 1 < nt) {
      STAGE32(t + 1, db ^ 1);
      asm volatile("s_waitcnt vmcnt(4)" ::: "memory");   // tile t landed; t+1 in flight
    } else {
      asm volatile("s_waitcnt vmcnt(0)" ::: "memory");
    }
    __builtin_amdgcn_s_barrier();

    const u16* Ab = &LA[db][0];
    const u16* Bb = &LB[db][0];

    bf16x8 af[4], bfr[4];
    #pragma unroll
    for (int i = 0; i < 4; i++) {
      const int ra = wr * 64 + i * 16 + frow;
      af[i]  = *(const bf16x8*)(Ab + ra * 32 + ((hi ^ (ra & 3)) << 3));
      const int rb = wc * 64 + i * 16 + frow;
      bfr[i] = *(const bf16x8*)(Bb + rb * 32 + ((hi ^ (rb & 3)) << 3));
    }
    __builtin_amdgcn_s_setprio(1);
    #pragma unroll
    for (int mi = 0; mi < 4; mi++)
      #pragma unroll
      for (int ni = 0; ni < 4; ni++)
        acc[mi][ni] = __builtin_amdgcn_mfma_f32_16x16x32_bf16(af[mi], bfr[ni], acc[mi][ni], 0, 0, 0);
    __builtin_amdgcn_s_setprio(0);
    __builtin_amdgcn_s_barrier();   // WAR: all waves done with buf db before restage
  }
  #undef STAGE32

  const int r0 = bm + wr * 64 + hi * 4;
  const int c0 = bn + wc * 64 + frow;
  #pragma unroll
  for (int mi = 0; mi < 4; mi++) {
    #pragma unroll
    for (int ni = 0; ni < 4; ni++) {
      #pragma unroll
      for (int r = 0; r < 4; r++) {
        float v = acc[mi][ni][r];
        const int rr = r0 + mi * 16 + r;
        const int cc = c0 + ni * 16;
        if (QKVE) {
          const int region = bn >> 10;            // 0=Q, 1=K, 2=V
          u16* qo = (u16*)Cout;
          u16* ko = qo + (size_t)4 * 1024 * 1024; // +8MB
          u16* vo = qo + (size_t)8 * 1024 * 1024; // +16MB
          const int c1 = cc & 1023;
          const int h = c1 >> 6, d = c1 & 63;
          const int bb2 = rr >> 11, t2 = rr & 2047;
          const int bh = bb2 * 16 + h;
          if (region == 0)
            qo[((size_t)bh * T_ + t2) * HD_ + d] = f2bf(v * 0.18033688011112042f);
          else if (region == 1)
            ko[((size_t)bh * T_ + t2) * HD_ + d] = f2bf(v);
          else
            vo[((size_t)bh * HD_ + d) * T_ + t2] = f2bf(v);
        } else if (PARTIAL) {
          ((float*)Cout)[((size_t)z * M + rr) * N + cc] = v;
        } else {
          if (BIAS) v += bias[cc];
          if (ACT == 1) {
            const float u = v * (0.79788456f + 0.03567740814f * v * v);
            const float e = exp2f(fminf(u * 2.885390082f, 80.f));
            v = v - v * __builtin_amdgcn_rcpf(1.0f + e);
          }
          if (resid) v += resid[(size_t)rr * N + cc];
          if (OUTBF) ((u16*)Cout)[(size_t)rr * N + cc] = f2bf(v);
          else       ((float*)Cout)[(size_t)rr * N + cc] = v;
        }
      }
    }
  }
}

// ---------------- split-K reduce: out = sum(parts) + bias (+resid), fp32
template<int NPART>
__global__ __launch_bounds__(256) void reduce_parts(
    const float* __restrict__ parts, const float* __restrict__ bias,
    const float* __restrict__ resid, float* __restrict__ out, int MN, int N) {
  const int i4 = (blockIdx.x * 256 + threadIdx.x) * 4;
  if (i4 >= MN) return;
  float4 s = *(const float4*)(parts + i4);
  #pragma unroll
  for (int p = 1; p < NPART; p++) {
    const float4 t = *(const float4*)(parts + (size_t)p * MN + i4);
    s.x += t.x; s.y += t.y; s.z += t.z; s.w += t.w;
  }
  const float4 bv = *(const float4*)(bias + (i4 & (N - 1)));
  const float4 rv = *(const float4*)(resid + i4);
  s.x += bv.x + rv.x; s.y += bv.y + rv.y; s.z += bv.z + rv.z; s.w += bv.w + rv.w;
  *(float4*)(out + i4) = s;
}

// ---------------- proj reduce (NPART=2) + bias + residual + LN2 fused.
__global__ __launch_bounds__(256) void reduce2_ln(
    const float* __restrict__ parts, const float* __restrict__ bias,
    const float* __restrict__ resid, const float* __restrict__ g,
    const float* __restrict__ bb, float* __restrict__ xout,
    u16* __restrict__ h2, int MN) {
  const int row = blockIdx.x, tid = threadIdx.x;
  const int i4 = row * D_ + tid * 4;
  float4 s = *(const float4*)(parts + i4);
  const float4 t = *(const float4*)(parts + (size_t)MN + i4);
  const float4 bv = *(const float4*)(bias + tid * 4);
  const float4 rv = *(const float4*)(resid + i4);
  s.x += t.x + bv.x + rv.x; s.y += t.y + bv.y + rv.y;
  s.z += t.z + bv.z + rv.z; s.w += t.w + bv.w + rv.w;
  *(float4*)(xout + i4) = s;
  float sm = s.x + s.y + s.z + s.w;
  float sq = s.x*s.x + s.y*s.y + s.z*s.z + s.w*s.w;
  #pragma unroll
  for (int m = 1; m < 64; m <<= 1) { sm += __shfl_xor(sm, m); sq += __shfl_xor(sq, m); }
  __shared__ float ss[4], qs[4];
  if ((tid & 63) == 0) { ss[tid >> 6] = sm; qs[tid >> 6] = sq; }
  __syncthreads();
  sm = ss[0] + ss[1] + ss[2] + ss[3];
  sq = qs[0] + qs[1] + qs[2] + qs[3];
  const float mean = sm * (1.f / D_);
  const float var  = sq * (1.f / D_) - mean * mean;
  const float rstd = rsqrtf(var + 1e-5f);
  const float4 gv = ((const float4*)g)[tid];
  const float4 b2v = ((const float4*)bb)[tid];
  u16 o[4];
  o[0] = f2bf((s.x - mean) * rstd * gv.x + b2v.x);
  o[1] = f2bf((s.y - mean) * rstd * gv.y + b2v.y);
  o[2] = f2bf((s.z - mean) * rstd * gv.z + b2v.z);
  o[3] = f2bf((s.w - mean) * rstd * gv.w + b2v.w);
  *(ushort4*)(h2 + (size_t)row * D_ + tid * 4) = *(ushort4*)o;
}

// ---------------- flash attention v7: 4-wave blocks, QBLK=64 (wave owns 16 rows),
// paired q-blocks (qb, 31-qb) -> 512 blocks x uniform 33 kv-tile rounds,
// 2 independent blocks/CU. XCD-bh locality, lazy row-max, ones-column l, defer-max.
__global__ __launch_bounds__(256, 2) void attn_fwd(
    const u16* __restrict__ q, const u16* __restrict__ k,
    const u16* __restrict__ vt, u16* __restrict__ out) {
  __shared__ __attribute__((aligned(16))) u16 Ps[4][16 * 64];   // 8KB
  __shared__ __attribute__((aligned(16))) u16 Kb[2][64 * 64];   // 16KB
  __shared__ __attribute__((aligned(16))) u16 Vb[2][64 * 64];   // 16KB

  const int bid = blockIdx.x;                // 512 blocks
  const int xcd = bid & 7, j = bid >> 3;     // j = 0..63
  const int bh  = xcd + 8 * (j & 3);         // 4 bh per xcd -> 2MB K/V, L2-resident
  const int qp  = j >> 2;                    // 0..15 -> q-blocks {qp, 31-qp}
  const int b = bh >> 4, h = bh & 15;
  const int tid = threadIdx.x, wid = tid >> 6, lane = tid & 63;
  const u16* kh = k  + (size_t)bh * T_ * HD_;
  const u16* vh = vt + (size_t)bh * HD_ * T_;

  const int frow = lane & 15;
  const int hi   = lane >> 4;
  const int fk   = hi * 8;
  const int rowb = hi * 4;
  const int colb = frow;
  const int srow = tid >> 3;                 // staging row 0..31 (per 32-row pass)
  const int gch  = (tid & 7) ^ (srow & 7);   // pre-swizzled chunk

  u16x8 onebits = (u16x8)((u16)0x3F80);
  bf16x8 b_one = (frow == 0) ? __builtin_bit_cast(bf16x8, onebits) : (bf16x8){};

  u16* Pw = &Ps[wid][0];

  for (int qi = 0; qi < 2; ++qi) {
    const int qb = qi ? (31 - qp) : qp;      // q-block of 64 rows
    const int q0 = qb * 64;
    const int nkt = qb + 1;

    const u16* qrow = q + ((size_t)bh * T_ + q0 + wid * 16 + frow) * HD_;
    bf16x8 aq[2];
    aq[0] = *(const bf16x8*)(qrow + fk);
    aq[1] = *(const bf16x8*)(qrow + 32 + fk);

    float m2[4] = {-3e38f, -3e38f, -3e38f, -3e38f};
    f32x4 acc_l = {};
    f32x4 acc_o[4] = {};

    int cur = 0;
    #pragma unroll
    for (int p = 0; p < 2; p++) {
      gload16(kh + (size_t)(p * 32 + srow) * HD_ + gch * 8, &Kb[0][(p * 32 + wid * 8) * 64]);
      gload16(vh + (size_t)(p * 32 + srow) * T_ + gch * 8,  &Vb[0][(p * 32 + wid * 8) * 64]);
    }
    __syncthreads();

    for (int kt = 0; kt < nkt; ++kt) {
      if (kt + 1 < nkt) {
        const int nx = cur ^ 1, ktn = kt + 1;
        #pragma unroll
        for (int p = 0; p < 2; p++) {
          gload16(kh + (size_t)(ktn * 64 + p * 32 + srow) * HD_ + gch * 8,
                  &Kb[nx][(p * 32 + wid * 8) * 64]);
          gload16(vh + (size_t)(p * 32 + srow) * T_ + ktn * 64 + gch * 8,
                  &Vb[nx][(p * 32 + wid * 8) * 64]);
        }
      }

      const u16* Kc = &Kb[cur][0];
      const u16* Vc = &Vb[cur][0];

      // ---- QK^T (q pre-scaled by 0.125*log2e)
      float p2[4][4];
      __builtin_amdgcn_s_setprio(1);
      #pragma unroll
      for (int ni = 0; ni < 4; ni++) {
        f32x4 s = {};
        #pragma unroll
        for (int ks = 0; ks < 2; ks++) {
          const int row = ni * 16 + frow;
          const int ch  = ks * 4 + hi;
          bf16x8 bk = *(const bf16x8*)(Kc + row * 64 + ((ch ^ (row & 7)) << 3));
          s = __builtin_amdgcn_mfma_f32_16x16x32_bf16(aq[ks], bk, s, 0, 0, 0);
        }
        #pragma unroll
        for (int r = 0; r < 4; r++) p2[ni][r] = s[r];
      }
      __builtin_amdgcn_s_setprio(0);

      if (kt == nkt - 1) {  // diagonal tile: mask cols > row
        #pragma unroll
        for (int ni = 0; ni < 4; ni++)
          #pragma unroll
          for (int r = 0; r < 4; r++) {
            const bool msk = (ni * 16 + colb) > (wid * 16 + rowb + r);
            if (msk) p2[ni][r] = -3e38f;
          }
      }

      // ---- lazy row max: local check, shuffles only on rescale events
      float lmax[4];
      #pragma unroll
      for (int r = 0; r < 4; r++)
        lmax[r] = fmaxf(fmaxf(p2[0][r], p2[1][r]), fmaxf(p2[2][r], p2[3][r]));
      int ok = 1;
      #pragma unroll
      for (int r = 0; r < 4; r++) ok &= (lmax[r] <= m2[r] + 8.0f);
      if (!__all(ok)) {
        #pragma unroll
        for (int r = 0; r < 4; r++) {
          float rm = lmax[r];
          rm = fmaxf(rm, __shfl_xor(rm, 1));
          rm = fmaxf(rm, __shfl_xor(rm, 2));
          rm = fmaxf(rm, __shfl_xor(rm, 4));
          rm = fmaxf(rm, __shfl_xor(rm, 8));
          const float mnew = fmaxf(m2[r], rm);
          const float corr = exp2f(m2[r] - mnew);
          m2[r] = mnew;
          acc_l[r] *= corr;
          #pragma unroll
          for (int ni = 0; ni < 4; ni++) acc_o[ni][r] *= corr;
        }
      }
      #pragma unroll
      for (int ni = 0; ni < 4; ni++)
        #pragma unroll
        for (int r = 0; r < 4; r++) p2[ni][r] = exp2f(p2[ni][r] - m2[r]);

      // ---- P -> per-wave swizzled LDS (cvt_pk), reload as A-frag
      #pragma unroll
      for (int ni = 0; ni < 4; ni++) {
        #pragma unroll
        for (int r = 0; r < 4; r += 2) {
          const unsigned pk = cvt_pk_bf16(p2[ni][r], p2[ni][r + 1]);
          const int lr0 = rowb + r, lr1 = rowb + r + 1;
          const int ch = ni * 2 + (colb >> 3);
          Pw[lr0 * 64 + ((ch ^ (lr0 & 7)) << 3) + (colb & 7)] = (u16)pk;
          Pw[lr1 * 64 + ((ch ^ (lr1 & 7)) << 3) + (colb & 7)] = (u16)(pk >> 16);
        }
      }
      bf16x8 ap[2];
      {
        const int c0 = (0 * 4 + hi) ^ (frow & 7);
        const int c1 = (1 * 4 + hi) ^ (frow & 7);
        ap[0] = *(const bf16x8*)(Pw + frow * 64 + (c0 << 3));
        ap[1] = *(const bf16x8*)(Pw + frow * 64 + (c1 << 3));
      }

      // ---- PV (+ ones-column for l)
      __builtin_amdgcn_s_setprio(1);
      #pragma unroll
      for (int ks = 0; ks < 2; ks++)
        acc_l = __builtin_amdgcn_mfma_f32_16x16x32_bf16(ap[ks], b_one, acc_l, 0, 0, 0);
      #pragma unroll
      for (int ni = 0; ni < 4; ni++) {
        #pragma unroll
        for (int ks = 0; ks < 2; ks++) {
          const int row = ni * 16 + frow;
          const int ch  = ks * 4 + hi;
          bf16x8 bv = *(const bf16x8*)(Vc + row * 64 + ((ch ^ (row & 7)) << 3));
          acc_o[ni] = __builtin_amdgcn_mfma_f32_16x16x32_bf16(ap[ks], bv, acc_o[ni], 0, 0, 0);
        }
      }
      __builtin_amdgcn_s_setprio(0);

      __syncthreads();
      cur ^= 1;
    }

    float linv[4];
    #pragma unroll
    for (int r = 0; r < 4; r++) {
      const float lv = __shfl(acc_l[r], lane & 48);
      linv[r] = 1.0f / lv;
    }
    #pragma unroll
    for (int ni = 0; ni < 4; ni++)
      #pragma unroll
      for (int r = 0; r < 4; r++) {
        const float ov = acc_o[ni][r] * linv[r];
        const size_t row = (size_t)b * T_ + q0 + wid * 16 + rowb + r;
        out[row * D_ + h * HD_ + ni * 16 + colb] = f2bf(ov);
      }
  }
}

extern "C" void kernel_launch(void* const* d_in, const int* in_sizes, int n_in,
                              void* d_out, int out_size, void* d_ws, size_t ws_size,
                              hipStream_t stream) {
  (void)in_sizes; (void)n_in; (void)out_size; (void)ws_size;
  const float* x      = (const float*)d_in[0];
  const float* wq     = (const float*)d_in[1];
  const float* wk     = (const float*)d_in[2];
  const float* wv     = (const float*)d_in[3];
  const float* w_proj = (const float*)d_in[4];
  const float* b_proj = (const float*)d_in[5];
  const float* ln1_g  = (const float*)d_in[6];
  const float* ln1_b  = (const float*)d_in[7];
  const float* ln2_g  = (const float*)d_in[8];
  const float* ln2_b  = (const float*)d_in[9];
  const float* w1     = (const float*)d_in[10];
  const float* b1     = (const float*)d_in[11];
  const float* w2     = (const float*)d_in[12];
  const float* b2     = (const float*)d_in[13];

  uint8_t* ws = (uint8_t*)d_ws;
  const size_t MB = 1024 * 1024;
  u16* wqkv_t = (u16*)(ws + 0);        // [3072,1024]
  u16* wproj_t = (u16*)(ws + 6 * MB);  // [1024,1024]
  u16* w1t  = (u16*)(ws + 8 * MB);     // [4096,1024]
  u16* w2t  = (u16*)(ws + 16 * MB);    // [1024,4096]
  u16* hbuf = (u16*)(ws + 24 * MB);    // [4096,1024]
  u16* qb   = (u16*)(ws + 56 * MB);    // [32,2048,64]  Q (scaled)
  u16* kb   = (u16*)(ws + 64 * MB);    // [32,2048,64]  K   (qb+8MB)
  u16* vtb  = (u16*)(ws + 72 * MB);    // [32,64,2048]  V^T (qb+16MB)
  u16* aout = (u16*)(ws + 80 * MB);    // [4096,1024]
  u16* h2   = (u16*)(ws + 88 * MB);    // [4096,1024]
  u16* ff1  = (u16*)(ws + 96 * MB);    // [4096,4096]
  float* pparts = (float*)(ws + 32 * MB);  // proj: 2 x [4096,1024] fp32 = 32 MB
  float* fparts = (float*)(ws + 32 * MB);  // ff2:  4 x [4096,1024] fp32 = 64 MB
  float* xout = (float*)d_out;

  prep_all<<<16384, dim3(32, 8), 0, stream>>>(
      wq, wk, wv, w_proj, w1, w2, wqkv_t, wproj_t, w1t, w2t,
      x, ln1_g, ln1_b, hbuf);

  // QKV GEMM with fused repack epilogue: writes q(scaled)/k/vt directly
  gemm128<0,0,0,0,1><<<dim3(3072/128, BT_/128), 256, 0, stream>>>(
      hbuf, wqkv_t, nullptr, nullptr, qb, BT_, 3072, D_, D_);

  attn_fwd<<<dim3(512), 256, 0, stream>>>(qb, kb, vtb, aout);

  // proj: split-K=2 partials, then fused reduce + bias + x-residual + LN2
  gemm128<0,0,0,1,0><<<dim3(D_/128, BT_/128, 2), 256, 0, stream>>>(
      aout, wproj_t, nullptr, nullptr, pparts, BT_, D_, D_, D_/2);
  reduce2_ln<<<BT_, 256, 0, stream>>>(
      pparts, b_proj, x, ln2_g, ln2_b, xout, h2, BT_*D_);

  // FF1: [4096,1024] x [4096,1024]^T -> GELU -> bf16 [4096,4096]
  gemm128<1,1,1,0,0><<<dim3(FF_/128, BT_/128), 256, 0, stream>>>(
      h2, w1t, b1, nullptr, ff1, BT_, FF_, D_, D_);

  // FF2: split-K=4 partials + fused reduce (bias + xout residual) -> xout in place
  gemm128<0,0,0,1,0><<<dim3(D_/128, BT_/128, 4), 256, 0, stream>>>(
      ff1, w2t, nullptr, nullptr, fparts, BT_, D_, FF_, FF_/4);
  reduce_parts<4><<<(BT_*D_)/1024, 256, 0, stream>>>(
      fparts, b2, xout, xout, BT_*D_, D_);
}

// Round 19
// 239.753 us; speedup vs baseline: 1.0371x; 1.0156x over previous
//
#include <hip/hip_runtime.h>
#include <hip/hip_bf16.h>
#include <cstdint>
#include <cstddef>
#include <math.h>

#define D_ 1024
#define H_ 16
#define HD_ 64
#define T_ 2048
#define B_ 2
#define FF_ 4096
#define BT_ (B_*T_)   // 4096 rows
#define NT_ 32        // T_/64 kv tiles

typedef unsigned short u16;
typedef __attribute__((ext_vector_type(8))) __bf16 bf16x8;
typedef __attribute__((ext_vector_type(8))) u16 u16x8;
typedef __attribute__((ext_vector_type(4))) float f32x4;

__device__ __forceinline__ u16 f2bf(float f) {
  unsigned u = __builtin_bit_cast(unsigned, f);
  u += 0x7FFFu + ((u >> 16) & 1u);
  return (u16)(u >> 16);
}

__device__ __forceinline__ unsigned cvt_pk_bf16(float a, float b) {
  unsigned r;
  asm("v_cvt_pk_bf16_f32 %0, %1, %2" : "=v"(r) : "v"(a), "v"(b));
  return r;
}

__device__ __forceinline__ void gload16(const void* g, void* l) {
  __builtin_amdgcn_global_load_lds((__attribute__((address_space(1))) void*)g,
                                   (__attribute__((address_space(3))) void*)l, 16, 0, 0);
}

// ---------------- fused prep: transpose+cast ALL weights AND LayerNorm1 (1 launch)
__global__ __launch_bounds__(256) void prep_all(
    const float* __restrict__ wq, const float* __restrict__ wk,
    const float* __restrict__ wv, const float* __restrict__ w_proj,
    const float* __restrict__ w1, const float* __restrict__ w2,
    u16* __restrict__ wqkv_t, u16* __restrict__ wproj_t,
    u16* __restrict__ w1t, u16* __restrict__ w2t,
    const float* __restrict__ x, const float* __restrict__ ln1_g,
    const float* __restrict__ ln1_b, u16* __restrict__ hbuf) {
  __shared__ float tile[32][33];
  __shared__ float ss[4], qs[4];
  const int bid = blockIdx.x;
  if (bid >= 12288) {
    const int row = bid - 12288;
    const int tid = threadIdx.y * 32 + threadIdx.x;
    const float4 v = ((const float4*)(x + (size_t)row * D_))[tid];
    float s = v.x + v.y + v.z + v.w;
    float sq = v.x*v.x + v.y*v.y + v.z*v.z + v.w*v.w;
    #pragma unroll
    for (int m = 1; m < 64; m <<= 1) { s += __shfl_xor(s, m); sq += __shfl_xor(sq, m); }
    if ((tid & 63) == 0) { ss[tid >> 6] = s; qs[tid >> 6] = sq; }
    __syncthreads();
    s  = ss[0] + ss[1] + ss[2] + ss[3];
    sq = qs[0] + qs[1] + qs[2] + qs[3];
    const float mean = s * (1.f / D_);
    const float var  = sq * (1.f / D_) - mean * mean;
    const float rstd = rsqrtf(var + 1e-5f);
    const float4 gv = ((const float4*)ln1_g)[tid];
    const float4 bv = ((const float4*)ln1_b)[tid];
    u16 o[4];
    o[0] = f2bf((v.x - mean) * rstd * gv.x + bv.x);
    o[1] = f2bf((v.y - mean) * rstd * gv.y + bv.y);
    o[2] = f2bf((v.z - mean) * rstd * gv.z + bv.z);
    o[3] = f2bf((v.w - mean) * rstd * gv.w + bv.w);
    *(ushort4*)(hbuf + (size_t)row * D_ + tid * 4) = *(ushort4*)o;
    return;
  }
  const float* in; u16* out; int R, C, tx, ty;
  if (bid < 3072) {
    const int w = bid >> 10, rem = bid & 1023;
    const int z = rem >> 6, t = rem & 63;
    tx = t & 1; ty = t >> 1;
    R = D_; C = HD_;
    in  = (w == 0 ? wq : w == 1 ? wk : wv) + (size_t)z * R * C;
    out = wqkv_t + (size_t)w * D_ * D_ + (size_t)z * C * R;
  } else if (bid < 4096) {
    const int t = bid - 3072;
    tx = t & 31; ty = t >> 5;
    R = D_; C = D_; in = w_proj; out = wproj_t;
  } else if (bid < 8192) {
    const int t = bid - 4096;
    tx = t & 127; ty = t >> 7;
    R = D_; C = FF_; in = w1; out = w1t;
  } else {
    const int t = bid - 8192;
    tx = t & 31; ty = t >> 5;
    R = FF_; C = D_; in = w2; out = w2t;
  }
  const int xx = tx * 32 + threadIdx.x;
  const int y0 = ty * 32 + threadIdx.y;
  #pragma unroll
  for (int j = 0; j < 32; j += 8)
    tile[threadIdx.y + j][threadIdx.x] = in[(size_t)(y0 + j) * C + xx];
  __syncthreads();
  const int orr = ty * 32 + threadIdx.x;
  const int oc0 = tx * 32 + threadIdx.y;
  #pragma unroll
  for (int j = 0; j < 32; j += 8)
    out[(size_t)(oc0 + j) * R + orr] = f2bf(tile[threadIdx.x][threadIdx.y + j]);
}

// ---------------- GEMM 128x128, BK=32, 4 waves, 32KB LDS -> 4 blocks/CU,
// counted-vmcnt stage-ahead + T1 XCD swizzle + conflict-free chunk^row XOR layout.
template<int ACT, int BIAS, int OUTBF, int PARTIAL, int QKVE>
__global__ __launch_bounds__(256, 4) void gemm128(
    const u16* __restrict__ A, const u16* __restrict__ Bt,
    const float* __restrict__ bias, const float* resid,
    void* Cout, int M, int N, int K, int Kper) {
  __shared__ __attribute__((aligned(16))) u16 LA[2][128 * 32];
  __shared__ __attribute__((aligned(16))) u16 LB[2][128 * 32];

  const int tid = threadIdx.x;
  const int wid = tid >> 6, lane = tid & 63;
  const int wr = wid >> 1, wc = wid & 1;
  const int frow = lane & 15, hi = lane >> 4;

  const int gx = gridDim.x;
  const int nwg = gx * gridDim.y;
  const int orig = blockIdx.y * gx + blockIdx.x;
  const int cpx = nwg >> 3;
  const int swz = (orig & 7) * cpx + (orig >> 3);
  const int bm = (swz / gx) * 128, bn = (swz % gx) * 128;
  const int z = PARTIAL ? blockIdx.z : 0;
  const int koff = z * Kper;
  const int nt = Kper >> 5;

  const int srow = tid >> 2;
  const int gch  = (tid & 3) ^ (srow & 3);
  const u16* Ag0 = A + (size_t)(bm + srow) * K + koff + gch * 8;
  const u16* Ag1 = Ag0 + (size_t)64 * K;
  const u16* Bg0 = Bt + (size_t)(bn + srow) * K + koff + gch * 8;
  const u16* Bg1 = Bg0 + (size_t)64 * K;
  const int ldsA0 = (wid * 16) * 32, ldsA1 = (64 + wid * 16) * 32;

  f32x4 acc[4][4] = {};

  #define STAGE32(kt, db)                              \
    {                                                  \
      const int ko = (kt) * 32;                        \
      gload16(Ag0 + ko, &LA[db][ldsA0]);               \
      gload16(Ag1 + ko, &LA[db][ldsA1]);               \
      gload16(Bg0 + ko, &LB[db][ldsA0]);               \
      gload16(Bg1 + ko, &LB[db][ldsA1]);               \
    }

  STAGE32(0, 0);

  for (int t = 0; t < nt; ++t) {
    const int db = t & 1;
    if (t + 1 < nt) {
      STAGE32(t + 1, db ^ 1);
      asm volatile("s_waitcnt vmcnt(4)" ::: "memory");
    } else {
      asm volatile("s_waitcnt vmcnt(0)" ::: "memory");
    }
    __builtin_amdgcn_s_barrier();

    const u16* Ab = &LA[db][0];
    const u16* Bb = &LB[db][0];

    bf16x8 af[4], bfr[4];
    #pragma unroll
    for (int i = 0; i < 4; i++) {
      const int ra = wr * 64 + i * 16 + frow;
      af[i]  = *(const bf16x8*)(Ab + ra * 32 + ((hi ^ (ra & 3)) << 3));
      const int rb = wc * 64 + i * 16 + frow;
      bfr[i] = *(const bf16x8*)(Bb + rb * 32 + ((hi ^ (rb & 3)) << 3));
    }
    __builtin_amdgcn_s_setprio(1);
    #pragma unroll
    for (int mi = 0; mi < 4; mi++)
      #pragma unroll
      for (int ni = 0; ni < 4; ni++)
        acc[mi][ni] = __builtin_amdgcn_mfma_f32_16x16x32_bf16(af[mi], bfr[ni], acc[mi][ni], 0, 0, 0);
    __builtin_amdgcn_s_setprio(0);
    __builtin_amdgcn_s_barrier();
  }
  #undef STAGE32

  const int r0 = bm + wr * 64 + hi * 4;
  const int c0 = bn + wc * 64 + frow;
  #pragma unroll
  for (int mi = 0; mi < 4; mi++) {
    #pragma unroll
    for (int ni = 0; ni < 4; ni++) {
      #pragma unroll
      for (int r = 0; r < 4; r++) {
        float v = acc[mi][ni][r];
        const int rr = r0 + mi * 16 + r;
        const int cc = c0 + ni * 16;
        if (QKVE) {
          const int region = bn >> 10;            // 0=Q, 1=K, 2=V
          u16* qo = (u16*)Cout;
          u16* ko = qo + (size_t)4 * 1024 * 1024; // +8MB
          u16* vo = qo + (size_t)8 * 1024 * 1024; // +16MB
          const int c1 = cc & 1023;
          const int h = c1 >> 6, d = c1 & 63;
          const int bb2 = rr >> 11, t2 = rr & 2047;
          const int bh = bb2 * 16 + h;
          if (region == 0)
            qo[((size_t)bh * T_ + t2) * HD_ + d] = f2bf(v * 0.18033688011112042f);
          else if (region == 1)
            ko[((size_t)bh * T_ + t2) * HD_ + d] = f2bf(v);
          else
            vo[((size_t)bh * HD_ + d) * T_ + t2] = f2bf(v);
        } else if (PARTIAL) {
          ((float*)Cout)[((size_t)z * M + rr) * N + cc] = v;
        } else {
          if (BIAS) v += bias[cc];
          if (ACT == 1) {
            const float u = v * (0.79788456f + 0.03567740814f * v * v);
            const float e = exp2f(fminf(u * 2.885390082f, 80.f));
            v = v - v * __builtin_amdgcn_rcpf(1.0f + e);
          }
          if (resid) v += resid[(size_t)rr * N + cc];
          if (OUTBF) ((u16*)Cout)[(size_t)rr * N + cc] = f2bf(v);
          else       ((float*)Cout)[(size_t)rr * N + cc] = v;
        }
      }
    }
  }
}

// ---------------- split-K reduce: out = sum(parts) + bias (+resid), fp32
template<int NPART>
__global__ __launch_bounds__(256) void reduce_parts(
    const float* __restrict__ parts, const float* __restrict__ bias,
    const float* __restrict__ resid, float* __restrict__ out, int MN, int N) {
  const int i4 = (blockIdx.x * 256 + threadIdx.x) * 4;
  if (i4 >= MN) return;
  float4 s = *(const float4*)(parts + i4);
  #pragma unroll
  for (int p = 1; p < NPART; p++) {
    const float4 t = *(const float4*)(parts + (size_t)p * MN + i4);
    s.x += t.x; s.y += t.y; s.z += t.z; s.w += t.w;
  }
  const float4 bv = *(const float4*)(bias + (i4 & (N - 1)));
  const float4 rv = *(const float4*)(resid + i4);
  s.x += bv.x + rv.x; s.y += bv.y + rv.y; s.z += bv.z + rv.z; s.w += bv.w + rv.w;
  *(float4*)(out + i4) = s;
}

// ---------------- proj reduce (NPART=2) + bias + residual + LN2 fused.
__global__ __launch_bounds__(256) void reduce2_ln(
    const float* __restrict__ parts, const float* __restrict__ bias,
    const float* __restrict__ resid, const float* __restrict__ g,
    const float* __restrict__ bb, float* __restrict__ xout,
    u16* __restrict__ h2, int MN) {
  const int row = blockIdx.x, tid = threadIdx.x;
  const int i4 = row * D_ + tid * 4;
  float4 s = *(const float4*)(parts + i4);
  const float4 t = *(const float4*)(parts + (size_t)MN + i4);
  const float4 bv = *(const float4*)(bias + tid * 4);
  const float4 rv = *(const float4*)(resid + i4);
  s.x += t.x + bv.x + rv.x; s.y += t.y + bv.y + rv.y;
  s.z += t.z + bv.z + rv.z; s.w += t.w + bv.w + rv.w;
  *(float4*)(xout + i4) = s;
  float sm = s.x + s.y + s.z + s.w;
  float sq = s.x*s.x + s.y*s.y + s.z*s.z + s.w*s.w;
  #pragma unroll
  for (int m = 1; m < 64; m <<= 1) { sm += __shfl_xor(sm, m); sq += __shfl_xor(sq, m); }
  __shared__ float ss[4], qs[4];
  if ((tid & 63) == 0) { ss[tid >> 6] = sm; qs[tid >> 6] = sq; }
  __syncthreads();
  sm = ss[0] + ss[1] + ss[2] + ss[3];
  sq = qs[0] + qs[1] + qs[2] + qs[3];
  const float mean = sm * (1.f / D_);
  const float var  = sq * (1.f / D_) - mean * mean;
  const float rstd = rsqrtf(var + 1e-5f);
  const float4 gv = ((const float4*)g)[tid];
  const float4 b2v = ((const float4*)bb)[tid];
  u16 o[4];
  o[0] = f2bf((s.x - mean) * rstd * gv.x + b2v.x);
  o[1] = f2bf((s.y - mean) * rstd * gv.y + b2v.y);
  o[2] = f2bf((s.z - mean) * rstd * gv.z + b2v.z);
  o[3] = f2bf((s.w - mean) * rstd * gv.w + b2v.w);
  *(ushort4*)(h2 + (size_t)row * D_ + tid * 4) = *(ushort4*)o;
}

// ---------------- flash attention v9: 1024 blocks, ONE 64-row q-block each.
// Per-CU quadruple {31-g, 16+g, 15-g, g} sums to 66 tile-rounds -> balanced at
// 3-4 co-resident blocks/CU (TLP that v6/v7 lacked); longest slots dispatched
// first. Body identical to v7 (proven correct). XCD-bh L2 locality kept.
__global__ __launch_bounds__(256, 2) void attn_fwd(
    const u16* __restrict__ q, const u16* __restrict__ k,
    const u16* __restrict__ vt, u16* __restrict__ out) {
  __shared__ __attribute__((aligned(16))) u16 Ps[4][16 * 64];   // 8KB
  __shared__ __attribute__((aligned(16))) u16 Kb[2][64 * 64];   // 16KB
  __shared__ __attribute__((aligned(16))) u16 Vb[2][64 * 64];   // 16KB

  const int bid = blockIdx.x;                // 1024 blocks
  const int xcd = bid & 7, j = bid >> 3;     // j = 0..127
  const int c   = j & 31, s = j >> 5;        // c: per-XCD cu index, s: slot 0..3
  const int bh  = xcd + 8 * (c >> 3);        // 4 bh per xcd -> 2MB K/V, L2-resident
  const int g   = c & 7;
  const int qb  = (s == 0) ? (31 - g) : (s == 1) ? (16 + g) : (s == 2) ? (15 - g) : g;
  const int b = bh >> 4, h = bh & 15;
  const int tid = threadIdx.x, wid = tid >> 6, lane = tid & 63;
  const u16* kh = k  + (size_t)bh * T_ * HD_;
  const u16* vh = vt + (size_t)bh * HD_ * T_;

  const int frow = lane & 15;
  const int hi   = lane >> 4;
  const int fk   = hi * 8;
  const int rowb = hi * 4;
  const int colb = frow;
  const int srow = tid >> 3;                 // staging row 0..31 (per 32-row pass)
  const int gch  = (tid & 7) ^ (srow & 7);   // pre-swizzled chunk

  u16x8 onebits = (u16x8)((u16)0x3F80);
  bf16x8 b_one = (frow == 0) ? __builtin_bit_cast(bf16x8, onebits) : (bf16x8){};

  u16* Pw = &Ps[wid][0];

  const int q0 = qb * 64;
  const int nkt = qb + 1;

  const u16* qrow = q + ((size_t)bh * T_ + q0 + wid * 16 + frow) * HD_;
  bf16x8 aq[2];
  aq[0] = *(const bf16x8*)(qrow + fk);
  aq[1] = *(const bf16x8*)(qrow + 32 + fk);

  float m2[4] = {-3e38f, -3e38f, -3e38f, -3e38f};
  f32x4 acc_l = {};
  f32x4 acc_o[4] = {};

  int cur = 0;
  #pragma unroll
  for (int p = 0; p < 2; p++) {
    gload16(kh + (size_t)(p * 32 + srow) * HD_ + gch * 8, &Kb[0][(p * 32 + wid * 8) * 64]);
    gload16(vh + (size_t)(p * 32 + srow) * T_ + gch * 8,  &Vb[0][(p * 32 + wid * 8) * 64]);
  }
  __syncthreads();

  for (int kt = 0; kt < nkt; ++kt) {
    if (kt + 1 < nkt) {
      const int nx = cur ^ 1, ktn = kt + 1;
      #pragma unroll
      for (int p = 0; p < 2; p++) {
        gload16(kh + (size_t)(ktn * 64 + p * 32 + srow) * HD_ + gch * 8,
                &Kb[nx][(p * 32 + wid * 8) * 64]);
        gload16(vh + (size_t)(p * 32 + srow) * T_ + ktn * 64 + gch * 8,
                &Vb[nx][(p * 32 + wid * 8) * 64]);
      }
    }

    const u16* Kc = &Kb[cur][0];
    const u16* Vc = &Vb[cur][0];

    // ---- QK^T (q pre-scaled by 0.125*log2e)
    float p2[4][4];
    __builtin_amdgcn_s_setprio(1);
    #pragma unroll
    for (int ni = 0; ni < 4; ni++) {
      f32x4 s2 = {};
      #pragma unroll
      for (int ks = 0; ks < 2; ks++) {
        const int row = ni * 16 + frow;
        const int ch  = ks * 4 + hi;
        bf16x8 bk = *(const bf16x8*)(Kc + row * 64 + ((ch ^ (row & 7)) << 3));
        s2 = __builtin_amdgcn_mfma_f32_16x16x32_bf16(aq[ks], bk, s2, 0, 0, 0);
      }
      #pragma unroll
      for (int r = 0; r < 4; r++) p2[ni][r] = s2[r];
    }
    __builtin_amdgcn_s_setprio(0);

    if (kt == nkt - 1) {  // diagonal tile: mask cols > row
      #pragma unroll
      for (int ni = 0; ni < 4; ni++)
        #pragma unroll
        for (int r = 0; r < 4; r++) {
          const bool msk = (ni * 16 + colb) > (wid * 16 + rowb + r);
          if (msk) p2[ni][r] = -3e38f;
        }
    }

    // ---- lazy row max: local check, shuffles only on rescale events
    float lmax[4];
    #pragma unroll
    for (int r = 0; r < 4; r++)
      lmax[r] = fmaxf(fmaxf(p2[0][r], p2[1][r]), fmaxf(p2[2][r], p2[3][r]));
    int ok = 1;
    #pragma unroll
    for (int r = 0; r < 4; r++) ok &= (lmax[r] <= m2[r] + 8.0f);
    if (!__all(ok)) {
      #pragma unroll
      for (int r = 0; r < 4; r++) {
        float rm = lmax[r];
        rm = fmaxf(rm, __shfl_xor(rm, 1));
        rm = fmaxf(rm, __shfl_xor(rm, 2));
        rm = fmaxf(rm, __shfl_xor(rm, 4));
        rm = fmaxf(rm, __shfl_xor(rm, 8));
        const float mnew = fmaxf(m2[r], rm);
        const float corr = exp2f(m2[r] - mnew);
        m2[r] = mnew;
        acc_l[r] *= corr;
        #pragma unroll
        for (int ni = 0; ni < 4; ni++) acc_o[ni][r] *= corr;
      }
    }
    #pragma unroll
    for (int ni = 0; ni < 4; ni++)
      #pragma unroll
      for (int r = 0; r < 4; r++) p2[ni][r] = exp2f(p2[ni][r] - m2[r]);

    // ---- P -> per-wave swizzled LDS (cvt_pk), reload as A-frag
    #pragma unroll
    for (int ni = 0; ni < 4; ni++) {
      #pragma unroll
      for (int r = 0; r < 4; r += 2) {
        const unsigned pk = cvt_pk_bf16(p2[ni][r], p2[ni][r + 1]);
        const int lr0 = rowb + r, lr1 = rowb + r + 1;
        const int ch = ni * 2 + (colb >> 3);
        Pw[lr0 * 64 + ((ch ^ (lr0 & 7)) << 3) + (colb & 7)] = (u16)pk;
        Pw[lr1 * 64 + ((ch ^ (lr1 & 7)) << 3) + (colb & 7)] = (u16)(pk >> 16);
      }
    }
    bf16x8 ap[2];
    {
      const int c0 = (0 * 4 + hi) ^ (frow & 7);
      const int c1 = (1 * 4 + hi) ^ (frow & 7);
      ap[0] = *(const bf16x8*)(Pw + frow * 64 + (c0 << 3));
      ap[1] = *(const bf16x8*)(Pw + frow * 64 + (c1 << 3));
    }

    // ---- PV (+ ones-column for l)
    __builtin_amdgcn_s_setprio(1);
    #pragma unroll
    for (int ks = 0; ks < 2; ks++)
      acc_l = __builtin_amdgcn_mfma_f32_16x16x32_bf16(ap[ks], b_one, acc_l, 0, 0, 0);
    #pragma unroll
    for (int ni = 0; ni < 4; ni++) {
      #pragma unroll
      for (int ks = 0; ks < 2; ks++) {
        const int row = ni * 16 + frow;
        const int ch  = ks * 4 + hi;
        bf16x8 bv = *(const bf16x8*)(Vc + row * 64 + ((ch ^ (row & 7)) << 3));
        acc_o[ni] = __builtin_amdgcn_mfma_f32_16x16x32_bf16(ap[ks], bv, acc_o[ni], 0, 0, 0);
      }
    }
    __builtin_amdgcn_s_setprio(0);

    __syncthreads();
    cur ^= 1;
  }

  float linv[4];
  #pragma unroll
  for (int r = 0; r < 4; r++) {
    const float lv = __shfl(acc_l[r], lane & 48);
    linv[r] = 1.0f / lv;
  }
  #pragma unroll
  for (int ni = 0; ni < 4; ni++)
    #pragma unroll
    for (int r = 0; r < 4; r++) {
      const float ov = acc_o[ni][r] * linv[r];
      const size_t row = (size_t)b * T_ + q0 + wid * 16 + rowb + r;
      out[row * D_ + h * HD_ + ni * 16 + colb] = f2bf(ov);
    }
}

extern "C" void kernel_launch(void* const* d_in, const int* in_sizes, int n_in,
                              void* d_out, int out_size, void* d_ws, size_t ws_size,
                              hipStream_t stream) {
  (void)in_sizes; (void)n_in; (void)out_size; (void)ws_size;
  const float* x      = (const float*)d_in[0];
  const float* wq     = (const float*)d_in[1];
  const float* wk     = (const float*)d_in[2];
  const float* wv     = (const float*)d_in[3];
  const float* w_proj = (const float*)d_in[4];
  const float* b_proj = (const float*)d_in[5];
  const float* ln1_g  = (const float*)d_in[6];
  const float* ln1_b  = (const float*)d_in[7];
  const float* ln2_g  = (const float*)d_in[8];
  const float* ln2_b  = (const float*)d_in[9];
  const float* w1     = (const float*)d_in[10];
  const float* b1     = (const float*)d_in[11];
  const float* w2     = (const float*)d_in[12];
  const float* b2     = (const float*)d_in[13];

  uint8_t* ws = (uint8_t*)d_ws;
  const size_t MB = 1024 * 1024;
  u16* wqkv_t = (u16*)(ws + 0);        // [3072,1024]
  u16* wproj_t = (u16*)(ws + 6 * MB);  // [1024,1024]
  u16* w1t  = (u16*)(ws + 8 * MB);     // [4096,1024]
  u16* w2t  = (u16*)(ws + 16 * MB);    // [1024,4096]
  u16* hbuf = (u16*)(ws + 24 * MB);    // [4096,1024]
  u16* qb   = (u16*)(ws + 56 * MB);    // [32,2048,64]  Q (scaled)
  u16* kb   = (u16*)(ws + 64 * MB);    // [32,2048,64]  K   (qb+8MB)
  u16* vtb  = (u16*)(ws + 72 * MB);    // [32,64,2048]  V^T (qb+16MB)
  u16* aout = (u16*)(ws + 80 * MB);    // [4096,1024]
  u16* h2   = (u16*)(ws + 88 * MB);    // [4096,1024]
  u16* ff1  = (u16*)(ws + 96 * MB);    // [4096,4096]
  float* pparts = (float*)(ws + 32 * MB);  // proj: 2 x [4096,1024] fp32 = 32 MB
  float* fparts = (float*)(ws + 32 * MB);  // ff2:  4 x [4096,1024] fp32 = 64 MB
  float* xout = (float*)d_out;

  prep_all<<<16384, dim3(32, 8), 0, stream>>>(
      wq, wk, wv, w_proj, w1, w2, wqkv_t, wproj_t, w1t, w2t,
      x, ln1_g, ln1_b, hbuf);

  // QKV GEMM with fused repack epilogue: writes q(scaled)/k/vt directly
  gemm128<0,0,0,0,1><<<dim3(3072/128, BT_/128), 256, 0, stream>>>(
      hbuf, wqkv_t, nullptr, nullptr, qb, BT_, 3072, D_, D_);

  attn_fwd<<<dim3(1024), 256, 0, stream>>>(qb, kb, vtb, aout);

  // proj: split-K=2 partials, then fused reduce + bias + x-residual + LN2
  gemm128<0,0,0,1,0><<<dim3(D_/128, BT_/128, 2), 256, 0, stream>>>(
      aout, wproj_t, nullptr, nullptr, pparts, BT_, D_, D_, D_/2);
  reduce2_ln<<<BT_, 256, 0, stream>>>(
      pparts, b_proj, x, ln2_g, ln2_b, xout, h2, BT_*D_);

  // FF1: [4096,1024] x [4096,1024]^T -> GELU -> bf16 [4096,4096]
  gemm128<1,1,1,0,0><<<dim3(FF_/128, BT_/128), 256, 0, stream>>>(
      h2, w1t, b1, nullptr, ff1, BT_, FF_, D_, D_);

  // FF2: split-K=4 partials + fused reduce (bias + xout residual) -> xout in place
  gemm128<0,0,0,1,0><<<dim3(D_/128, BT_/128, 4), 256, 0, stream>>>(
      ff1, w2t, nullptr, nullptr, fparts, BT_, D_, FF_, FF_/4);
  reduce_parts<4><<<(BT_*D_)/1024, 256, 0, stream>>>(
      fparts, b2, xout, xout, BT_*D_, D_);
}

// Round 20
// 237.878 us; speedup vs baseline: 1.0453x; 1.0079x over previous
//
#include <hip/hip_runtime.h>
#include <hip/hip_bf16.h>
#include <cstdint>
#include <cstddef>
#include <math.h>

#define D_ 1024
#define H_ 16
#define HD_ 64
#define T_ 2048
#define B_ 2
#define FF_ 4096
#define BT_ (B_*T_)   // 4096 rows
#define NT_ 32        // T_/64 kv tiles

typedef unsigned short u16;
typedef __attribute__((ext_vector_type(8))) __bf16 bf16x8;
typedef __attribute__((ext_vector_type(8))) u16 u16x8;
typedef __attribute__((ext_vector_type(4))) float f32x4;

__device__ __forceinline__ u16 f2bf(float f) {
  unsigned u = __builtin_bit_cast(unsigned, f);
  u += 0x7FFFu + ((u >> 16) & 1u);
  return (u16)(u >> 16);
}

__device__ __forceinline__ unsigned cvt_pk_bf16(float a, float b) {
  unsigned r;
  asm("v_cvt_pk_bf16_f32 %0, %1, %2" : "=v"(r) : "v"(a), "v"(b));
  return r;
}

__device__ __forceinline__ void gload16(const void* g, void* l) {
  __builtin_amdgcn_global_load_lds((__attribute__((address_space(1))) void*)g,
                                   (__attribute__((address_space(3))) void*)l, 16, 0, 0);
}

// ---------------- fused prep: transpose+cast ALL weights AND LayerNorm1 (1 launch)
__global__ __launch_bounds__(256) void prep_all(
    const float* __restrict__ wq, const float* __restrict__ wk,
    const float* __restrict__ wv, const float* __restrict__ w_proj,
    const float* __restrict__ w1, const float* __restrict__ w2,
    u16* __restrict__ wqkv_t, u16* __restrict__ wproj_t,
    u16* __restrict__ w1t, u16* __restrict__ w2t,
    const float* __restrict__ x, const float* __restrict__ ln1_g,
    const float* __restrict__ ln1_b, u16* __restrict__ hbuf) {
  __shared__ float tile[32][33];
  __shared__ float ss[4], qs[4];
  const int bid = blockIdx.x;
  if (bid >= 12288) {
    const int row = bid - 12288;
    const int tid = threadIdx.y * 32 + threadIdx.x;
    const float4 v = ((const float4*)(x + (size_t)row * D_))[tid];
    float s = v.x + v.y + v.z + v.w;
    float sq = v.x*v.x + v.y*v.y + v.z*v.z + v.w*v.w;
    #pragma unroll
    for (int m = 1; m < 64; m <<= 1) { s += __shfl_xor(s, m); sq += __shfl_xor(sq, m); }
    if ((tid & 63) == 0) { ss[tid >> 6] = s; qs[tid >> 6] = sq; }
    __syncthreads();
    s  = ss[0] + ss[1] + ss[2] + ss[3];
    sq = qs[0] + qs[1] + qs[2] + qs[3];
    const float mean = s * (1.f / D_);
    const float var  = sq * (1.f / D_) - mean * mean;
    const float rstd = rsqrtf(var + 1e-5f);
    const float4 gv = ((const float4*)ln1_g)[tid];
    const float4 bv = ((const float4*)ln1_b)[tid];
    u16 o[4];
    o[0] = f2bf((v.x - mean) * rstd * gv.x + bv.x);
    o[1] = f2bf((v.y - mean) * rstd * gv.y + bv.y);
    o[2] = f2bf((v.z - mean) * rstd * gv.z + bv.z);
    o[3] = f2bf((v.w - mean) * rstd * gv.w + bv.w);
    *(ushort4*)(hbuf + (size_t)row * D_ + tid * 4) = *(ushort4*)o;
    return;
  }
  const float* in; u16* out; int R, C, tx, ty;
  if (bid < 3072) {
    const int w = bid >> 10, rem = bid & 1023;
    const int z = rem >> 6, t = rem & 63;
    tx = t & 1; ty = t >> 1;
    R = D_; C = HD_;
    in  = (w == 0 ? wq : w == 1 ? wk : wv) + (size_t)z * R * C;
    out = wqkv_t + (size_t)w * D_ * D_ + (size_t)z * C * R;
  } else if (bid < 4096) {
    const int t = bid - 3072;
    tx = t & 31; ty = t >> 5;
    R = D_; C = D_; in = w_proj; out = wproj_t;
  } else if (bid < 8192) {
    const int t = bid - 4096;
    tx = t & 127; ty = t >> 7;
    R = D_; C = FF_; in = w1; out = w1t;
  } else {
    const int t = bid - 8192;
    tx = t & 31; ty = t >> 5;
    R = FF_; C = D_; in = w2; out = w2t;
  }
  const int xx = tx * 32 + threadIdx.x;
  const int y0 = ty * 32 + threadIdx.y;
  #pragma unroll
  for (int j = 0; j < 32; j += 8)
    tile[threadIdx.y + j][threadIdx.x] = in[(size_t)(y0 + j) * C + xx];
  __syncthreads();
  const int orr = ty * 32 + threadIdx.x;
  const int oc0 = tx * 32 + threadIdx.y;
  #pragma unroll
  for (int j = 0; j < 32; j += 8)
    out[(size_t)(oc0 + j) * R + orr] = f2bf(tile[threadIdx.x][threadIdx.y + j]);
}

// ---------------- GEMM 128x128, BK=32, 4 waves, 32KB LDS -> 4 blocks/CU,
// counted-vmcnt stage-ahead + T1 XCD swizzle.
// Bank-conflict-free chunk XOR: f(row) = (row>>1)&3 (round-19 fix: with 64B rows,
// f=row&3 left the per-cycle 4-bank-group index covering only 4 of 8 groups ->
// 2-way conflict every cycle; (row>>1)&3 makes (row&1, hi^f) cover all 8).
template<int ACT, int BIAS, int OUTBF, int PARTIAL, int QKVE>
__global__ __launch_bounds__(256, 4) void gemm128(
    const u16* __restrict__ A, const u16* __restrict__ Bt,
    const float* __restrict__ bias, const float* resid,
    void* Cout, int M, int N, int K, int Kper) {
  __shared__ __attribute__((aligned(16))) u16 LA[2][128 * 32];
  __shared__ __attribute__((aligned(16))) u16 LB[2][128 * 32];

  const int tid = threadIdx.x;
  const int wid = tid >> 6, lane = tid & 63;
  const int wr = wid >> 1, wc = wid & 1;
  const int frow = lane & 15, hi = lane >> 4;

  const int gx = gridDim.x;
  const int nwg = gx * gridDim.y;
  const int orig = blockIdx.y * gx + blockIdx.x;
  const int cpx = nwg >> 3;
  const int swz = (orig & 7) * cpx + (orig >> 3);
  const int bm = (swz / gx) * 128, bn = (swz % gx) * 128;
  const int z = PARTIAL ? blockIdx.z : 0;
  const int koff = z * Kper;
  const int nt = Kper >> 5;

  const int srow = tid >> 2;
  const int gch  = (tid & 3) ^ ((srow >> 1) & 3);
  const u16* Ag0 = A + (size_t)(bm + srow) * K + koff + gch * 8;
  const u16* Ag1 = Ag0 + (size_t)64 * K;
  const u16* Bg0 = Bt + (size_t)(bn + srow) * K + koff + gch * 8;
  const u16* Bg1 = Bg0 + (size_t)64 * K;
  const int ldsA0 = (wid * 16) * 32, ldsA1 = (64 + wid * 16) * 32;

  f32x4 acc[4][4] = {};

  #define STAGE32(kt, db)                              \
    {                                                  \
      const int ko = (kt) * 32;                        \
      gload16(Ag0 + ko, &LA[db][ldsA0]);               \
      gload16(Ag1 + ko, &LA[db][ldsA1]);               \
      gload16(Bg0 + ko, &LB[db][ldsA0]);               \
      gload16(Bg1 + ko, &LB[db][ldsA1]);               \
    }

  STAGE32(0, 0);

  for (int t = 0; t < nt; ++t) {
    const int db = t & 1;
    if (t + 1 < nt) {
      STAGE32(t + 1, db ^ 1);
      asm volatile("s_waitcnt vmcnt(4)" ::: "memory");
    } else {
      asm volatile("s_waitcnt vmcnt(0)" ::: "memory");
    }
    __builtin_amdgcn_s_barrier();

    const u16* Ab = &LA[db][0];
    const u16* Bb = &LB[db][0];

    bf16x8 af[4], bfr[4];
    #pragma unroll
    for (int i = 0; i < 4; i++) {
      const int ra = wr * 64 + i * 16 + frow;
      af[i]  = *(const bf16x8*)(Ab + ra * 32 + ((hi ^ ((ra >> 1) & 3)) << 3));
      const int rb = wc * 64 + i * 16 + frow;
      bfr[i] = *(const bf16x8*)(Bb + rb * 32 + ((hi ^ ((rb >> 1) & 3)) << 3));
    }
    __builtin_amdgcn_s_setprio(1);
    #pragma unroll
    for (int mi = 0; mi < 4; mi++)
      #pragma unroll
      for (int ni = 0; ni < 4; ni++)
        acc[mi][ni] = __builtin_amdgcn_mfma_f32_16x16x32_bf16(af[mi], bfr[ni], acc[mi][ni], 0, 0, 0);
    __builtin_amdgcn_s_setprio(0);
    __builtin_amdgcn_s_barrier();
  }
  #undef STAGE32

  const int r0 = bm + wr * 64 + hi * 4;
  const int c0 = bn + wc * 64 + frow;
  #pragma unroll
  for (int mi = 0; mi < 4; mi++) {
    #pragma unroll
    for (int ni = 0; ni < 4; ni++) {
      #pragma unroll
      for (int r = 0; r < 4; r++) {
        float v = acc[mi][ni][r];
        const int rr = r0 + mi * 16 + r;
        const int cc = c0 + ni * 16;
        if (QKVE) {
          const int region = bn >> 10;            // 0=Q, 1=K, 2=V
          u16* qo = (u16*)Cout;
          u16* ko = qo + (size_t)4 * 1024 * 1024; // +8MB
          u16* vo = qo + (size_t)8 * 1024 * 1024; // +16MB
          const int c1 = cc & 1023;
          const int h = c1 >> 6, d = c1 & 63;
          const int bb2 = rr >> 11, t2 = rr & 2047;
          const int bh = bb2 * 16 + h;
          if (region == 0)
            qo[((size_t)bh * T_ + t2) * HD_ + d] = f2bf(v * 0.18033688011112042f);
          else if (region == 1)
            ko[((size_t)bh * T_ + t2) * HD_ + d] = f2bf(v);
          else
            vo[((size_t)bh * HD_ + d) * T_ + t2] = f2bf(v);
        } else if (PARTIAL) {
          ((float*)Cout)[((size_t)z * M + rr) * N + cc] = v;
        } else {
          if (BIAS) v += bias[cc];
          if (ACT == 1) {
            const float u = v * (0.79788456f + 0.03567740814f * v * v);
            const float e = exp2f(fminf(u * 2.885390082f, 80.f));
            v = v - v * __builtin_amdgcn_rcpf(1.0f + e);
          }
          if (resid) v += resid[(size_t)rr * N + cc];
          if (OUTBF) ((u16*)Cout)[(size_t)rr * N + cc] = f2bf(v);
          else       ((float*)Cout)[(size_t)rr * N + cc] = v;
        }
      }
    }
  }
}

// ---------------- split-K reduce: out = sum(parts) + bias (+resid), fp32
template<int NPART>
__global__ __launch_bounds__(256) void reduce_parts(
    const float* __restrict__ parts, const float* __restrict__ bias,
    const float* __restrict__ resid, float* __restrict__ out, int MN, int N) {
  const int i4 = (blockIdx.x * 256 + threadIdx.x) * 4;
  if (i4 >= MN) return;
  float4 s = *(const float4*)(parts + i4);
  #pragma unroll
  for (int p = 1; p < NPART; p++) {
    const float4 t = *(const float4*)(parts + (size_t)p * MN + i4);
    s.x += t.x; s.y += t.y; s.z += t.z; s.w += t.w;
  }
  const float4 bv = *(const float4*)(bias + (i4 & (N - 1)));
  const float4 rv = *(const float4*)(resid + i4);
  s.x += bv.x + rv.x; s.y += bv.y + rv.y; s.z += bv.z + rv.z; s.w += bv.w + rv.w;
  *(float4*)(out + i4) = s;
}

// ---------------- proj reduce (NPART=2) + bias + residual + LN2 fused.
__global__ __launch_bounds__(256) void reduce2_ln(
    const float* __restrict__ parts, const float* __restrict__ bias,
    const float* __restrict__ resid, const float* __restrict__ g,
    const float* __restrict__ bb, float* __restrict__ xout,
    u16* __restrict__ h2, int MN) {
  const int row = blockIdx.x, tid = threadIdx.x;
  const int i4 = row * D_ + tid * 4;
  float4 s = *(const float4*)(parts + i4);
  const float4 t = *(const float4*)(parts + (size_t)MN + i4);
  const float4 bv = *(const float4*)(bias + tid * 4);
  const float4 rv = *(const float4*)(resid + i4);
  s.x += t.x + bv.x + rv.x; s.y += t.y + bv.y + rv.y;
  s.z += t.z + bv.z + rv.z; s.w += t.w + bv.w + rv.w;
  *(float4*)(xout + i4) = s;
  float sm = s.x + s.y + s.z + s.w;
  float sq = s.x*s.x + s.y*s.y + s.z*s.z + s.w*s.w;
  #pragma unroll
  for (int m = 1; m < 64; m <<= 1) { sm += __shfl_xor(sm, m); sq += __shfl_xor(sq, m); }
  __shared__ float ss[4], qs[4];
  if ((tid & 63) == 0) { ss[tid >> 6] = sm; qs[tid >> 6] = sq; }
  __syncthreads();
  sm = ss[0] + ss[1] + ss[2] + ss[3];
  sq = qs[0] + qs[1] + qs[2] + qs[3];
  const float mean = sm * (1.f / D_);
  const float var  = sq * (1.f / D_) - mean * mean;
  const float rstd = rsqrtf(var + 1e-5f);
  const float4 gv = ((const float4*)g)[tid];
  const float4 b2v = ((const float4*)bb)[tid];
  u16 o[4];
  o[0] = f2bf((s.x - mean) * rstd * gv.x + b2v.x);
  o[1] = f2bf((s.y - mean) * rstd * gv.y + b2v.y);
  o[2] = f2bf((s.z - mean) * rstd * gv.z + b2v.z);
  o[3] = f2bf((s.w - mean) * rstd * gv.w + b2v.w);
  *(ushort4*)(h2 + (size_t)row * D_ + tid * 4) = *(ushort4*)o;
}

// ---------------- flash attention v9: 1024 blocks, ONE 64-row q-block each.
// Per-CU quadruple {31-g, 16+g, 15-g, g} sums to 66 tile-rounds -> balanced at
// 3-4 co-resident blocks/CU; XCD-bh L2 locality; v7 body.
__global__ __launch_bounds__(256, 2) void attn_fwd(
    const u16* __restrict__ q, const u16* __restrict__ k,
    const u16* __restrict__ vt, u16* __restrict__ out) {
  __shared__ __attribute__((aligned(16))) u16 Ps[4][16 * 64];   // 8KB
  __shared__ __attribute__((aligned(16))) u16 Kb[2][64 * 64];   // 16KB
  __shared__ __attribute__((aligned(16))) u16 Vb[2][64 * 64];   // 16KB

  const int bid = blockIdx.x;                // 1024 blocks
  const int xcd = bid & 7, j = bid >> 3;     // j = 0..127
  const int c   = j & 31, s = j >> 5;        // c: per-XCD cu index, s: slot 0..3
  const int bh  = xcd + 8 * (c >> 3);        // 4 bh per xcd -> 2MB K/V, L2-resident
  const int g   = c & 7;
  const int qb  = (s == 0) ? (31 - g) : (s == 1) ? (16 + g) : (s == 2) ? (15 - g) : g;
  const int b = bh >> 4, h = bh & 15;
  const int tid = threadIdx.x, wid = tid >> 6, lane = tid & 63;
  const u16* kh = k  + (size_t)bh * T_ * HD_;
  const u16* vh = vt + (size_t)bh * HD_ * T_;

  const int frow = lane & 15;
  const int hi   = lane >> 4;
  const int fk   = hi * 8;
  const int rowb = hi * 4;
  const int colb = frow;
  const int srow = tid >> 3;                 // staging row 0..31 (per 32-row pass)
  const int gch  = (tid & 7) ^ (srow & 7);   // pre-swizzled chunk

  u16x8 onebits = (u16x8)((u16)0x3F80);
  bf16x8 b_one = (frow == 0) ? __builtin_bit_cast(bf16x8, onebits) : (bf16x8){};

  u16* Pw = &Ps[wid][0];

  const int q0 = qb * 64;
  const int nkt = qb + 1;

  const u16* qrow = q + ((size_t)bh * T_ + q0 + wid * 16 + frow) * HD_;
  bf16x8 aq[2];
  aq[0] = *(const bf16x8*)(qrow + fk);
  aq[1] = *(const bf16x8*)(qrow + 32 + fk);

  float m2[4] = {-3e38f, -3e38f, -3e38f, -3e38f};
  f32x4 acc_l = {};
  f32x4 acc_o[4] = {};

  int cur = 0;
  #pragma unroll
  for (int p = 0; p < 2; p++) {
    gload16(kh + (size_t)(p * 32 + srow) * HD_ + gch * 8, &Kb[0][(p * 32 + wid * 8) * 64]);
    gload16(vh + (size_t)(p * 32 + srow) * T_ + gch * 8,  &Vb[0][(p * 32 + wid * 8) * 64]);
  }
  __syncthreads();

  for (int kt = 0; kt < nkt; ++kt) {
    if (kt + 1 < nkt) {
      const int nx = cur ^ 1, ktn = kt + 1;
      #pragma unroll
      for (int p = 0; p < 2; p++) {
        gload16(kh + (size_t)(ktn * 64 + p * 32 + srow) * HD_ + gch * 8,
                &Kb[nx][(p * 32 + wid * 8) * 64]);
        gload16(vh + (size_t)(p * 32 + srow) * T_ + ktn * 64 + gch * 8,
                &Vb[nx][(p * 32 + wid * 8) * 64]);
      }
    }

    const u16* Kc = &Kb[cur][0];
    const u16* Vc = &Vb[cur][0];

    // ---- QK^T (q pre-scaled by 0.125*log2e)
    float p2[4][4];
    __builtin_amdgcn_s_setprio(1);
    #pragma unroll
    for (int ni = 0; ni < 4; ni++) {
      f32x4 s2 = {};
      #pragma unroll
      for (int ks = 0; ks < 2; ks++) {
        const int row = ni * 16 + frow;
        const int ch  = ks * 4 + hi;
        bf16x8 bk = *(const bf16x8*)(Kc + row * 64 + ((ch ^ (row & 7)) << 3));
        s2 = __builtin_amdgcn_mfma_f32_16x16x32_bf16(aq[ks], bk, s2, 0, 0, 0);
      }
      #pragma unroll
      for (int r = 0; r < 4; r++) p2[ni][r] = s2[r];
    }
    __builtin_amdgcn_s_setprio(0);

    if (kt == nkt - 1) {  // diagonal tile: mask cols > row
      #pragma unroll
      for (int ni = 0; ni < 4; ni++)
        #pragma unroll
        for (int r = 0; r < 4; r++) {
          const bool msk = (ni * 16 + colb) > (wid * 16 + rowb + r);
          if (msk) p2[ni][r] = -3e38f;
        }
    }

    // ---- lazy row max: local check, shuffles only on rescale events
    float lmax[4];
    #pragma unroll
    for (int r = 0; r < 4; r++)
      lmax[r] = fmaxf(fmaxf(p2[0][r], p2[1][r]), fmaxf(p2[2][r], p2[3][r]));
    int ok = 1;
    #pragma unroll
    for (int r = 0; r < 4; r++) ok &= (lmax[r] <= m2[r] + 8.0f);
    if (!__all(ok)) {
      #pragma unroll
      for (int r = 0; r < 4; r++) {
        float rm = lmax[r];
        rm = fmaxf(rm, __shfl_xor(rm, 1));
        rm = fmaxf(rm, __shfl_xor(rm, 2));
        rm = fmaxf(rm, __shfl_xor(rm, 4));
        rm = fmaxf(rm, __shfl_xor(rm, 8));
        const float mnew = fmaxf(m2[r], rm);
        const float corr = exp2f(m2[r] - mnew);
        m2[r] = mnew;
        acc_l[r] *= corr;
        #pragma unroll
        for (int ni = 0; ni < 4; ni++) acc_o[ni][r] *= corr;
      }
    }
    #pragma unroll
    for (int ni = 0; ni < 4; ni++)
      #pragma unroll
      for (int r = 0; r < 4; r++) p2[ni][r] = exp2f(p2[ni][r] - m2[r]);

    // ---- P -> per-wave swizzled LDS (cvt_pk), reload as A-frag
    #pragma unroll
    for (int ni = 0; ni < 4; ni++) {
      #pragma unroll
      for (int r = 0; r < 4; r += 2) {
        const unsigned pk = cvt_pk_bf16(p2[ni][r], p2[ni][r + 1]);
        const int lr0 = rowb + r, lr1 = rowb + r + 1;
        const int ch = ni * 2 + (colb >> 3);
        Pw[lr0 * 64 + ((ch ^ (lr0 & 7)) << 3) + (colb & 7)] = (u16)pk;
        Pw[lr1 * 64 + ((ch ^ (lr1 & 7)) << 3) + (colb & 7)] = (u16)(pk >> 16);
      }
    }
    bf16x8 ap[2];
    {
      const int c0 = (0 * 4 + hi) ^ (frow & 7);
      const int c1 = (1 * 4 + hi) ^ (frow & 7);
      ap[0] = *(const bf16x8*)(Pw + frow * 64 + (c0 << 3));
      ap[1] = *(const bf16x8*)(Pw + frow * 64 + (c1 << 3));
    }

    // ---- PV (+ ones-column for l)
    __builtin_amdgcn_s_setprio(1);
    #pragma unroll
    for (int ks = 0; ks < 2; ks++)
      acc_l = __builtin_amdgcn_mfma_f32_16x16x32_bf16(ap[ks], b_one, acc_l, 0, 0, 0);
    #pragma unroll
    for (int ni = 0; ni < 4; ni++) {
      #pragma unroll
      for (int ks = 0; ks < 2; ks++) {
        const int row = ni * 16 + frow;
        const int ch  = ks * 4 + hi;
        bf16x8 bv = *(const bf16x8*)(Vc + row * 64 + ((ch ^ (row & 7)) << 3));
        acc_o[ni] = __builtin_amdgcn_mfma_f32_16x16x32_bf16(ap[ks], bv, acc_o[ni], 0, 0, 0);
      }
    }
    __builtin_amdgcn_s_setprio(0);

    __syncthreads();
    cur ^= 1;
  }

  float linv[4];
  #pragma unroll
  for (int r = 0; r < 4; r++) {
    const float lv = __shfl(acc_l[r], lane & 48);
    linv[r] = 1.0f / lv;
  }
  #pragma unroll
  for (int ni = 0; ni < 4; ni++)
    #pragma unroll
    for (int r = 0; r < 4; r++) {
      const float ov = acc_o[ni][r] * linv[r];
      const size_t row = (size_t)b * T_ + q0 + wid * 16 + rowb + r;
      out[row * D_ + h * HD_ + ni * 16 + colb] = f2bf(ov);
    }
}

extern "C" void kernel_launch(void* const* d_in, const int* in_sizes, int n_in,
                              void* d_out, int out_size, void* d_ws, size_t ws_size,
                              hipStream_t stream) {
  (void)in_sizes; (void)n_in; (void)out_size; (void)ws_size;
  const float* x      = (const float*)d_in[0];
  const float* wq     = (const float*)d_in[1];
  const float* wk     = (const float*)d_in[2];
  const float* wv     = (const float*)d_in[3];
  const float* w_proj = (const float*)d_in[4];
  const float* b_proj = (const float*)d_in[5];
  const float* ln1_g  = (const float*)d_in[6];
  const float* ln1_b  = (const float*)d_in[7];
  const float* ln2_g  = (const float*)d_in[8];
  const float* ln2_b  = (const float*)d_in[9];
  const float* w1     = (const float*)d_in[10];
  const float* b1     = (const float*)d_in[11];
  const float* w2     = (const float*)d_in[12];
  const float* b2     = (const float*)d_in[13];

  uint8_t* ws = (uint8_t*)d_ws;
  const size_t MB = 1024 * 1024;
  u16* wqkv_t = (u16*)(ws + 0);        // [3072,1024]
  u16* wproj_t = (u16*)(ws + 6 * MB);  // [1024,1024]
  u16* w1t  = (u16*)(ws + 8 * MB);     // [4096,1024]
  u16* w2t  = (u16*)(ws + 16 * MB);    // [1024,4096]
  u16* hbuf = (u16*)(ws + 24 * MB);    // [4096,1024]
  u16* qb   = (u16*)(ws + 56 * MB);    // [32,2048,64]  Q (scaled)
  u16* kb   = (u16*)(ws + 64 * MB);    // [32,2048,64]  K   (qb+8MB)
  u16* vtb  = (u16*)(ws + 72 * MB);    // [32,64,2048]  V^T (qb+16MB)
  u16* aout = (u16*)(ws + 80 * MB);    // [4096,1024]
  u16* h2   = (u16*)(ws + 88 * MB);    // [4096,1024]
  u16* ff1  = (u16*)(ws + 96 * MB);    // [4096,4096]
  float* pparts = (float*)(ws + 32 * MB);  // proj: 2 x [4096,1024] fp32 = 32 MB
  float* fparts = (float*)(ws + 32 * MB);  // ff2:  4 x [4096,1024] fp32 = 64 MB
  float* xout = (float*)d_out;

  prep_all<<<16384, dim3(32, 8), 0, stream>>>(
      wq, wk, wv, w_proj, w1, w2, wqkv_t, wproj_t, w1t, w2t,
      x, ln1_g, ln1_b, hbuf);

  // QKV GEMM with fused repack epilogue: writes q(scaled)/k/vt directly
  gemm128<0,0,0,0,1><<<dim3(3072/128, BT_/128), 256, 0, stream>>>(
      hbuf, wqkv_t, nullptr, nullptr, qb, BT_, 3072, D_, D_);

  attn_fwd<<<dim3(1024), 256, 0, stream>>>(qb, kb, vtb, aout);

  // proj: split-K=2 partials, then fused reduce + bias + x-residual + LN2
  gemm128<0,0,0,1,0><<<dim3(D_/128, BT_/128, 2), 256, 0, stream>>>(
      aout, wproj_t, nullptr, nullptr, pparts, BT_, D_, D_, D_/2);
  reduce2_ln<<<BT_, 256, 0, stream>>>(
      pparts, b_proj, x, ln2_g, ln2_b, xout, h2, BT_*D_);

  // FF1: [4096,1024] x [4096,1024]^T -> GELU -> bf16 [4096,4096]
  gemm128<1,1,1,0,0><<<dim3(FF_/128, BT_/128), 256, 0, stream>>>(
      h2, w1t, b1, nullptr, ff1, BT_, FF_, D_, D_);

  // FF2: split-K=4 partials + fused reduce (bias + xout residual) -> xout in place
  gemm128<0,0,0,1,0><<<dim3(D_/128, BT_/128, 4), 256, 0, stream>>>(
      ff1, w2t, nullptr, nullptr, fparts, BT_, D_, FF_, FF_/4);
  reduce_parts<4><<<(BT_*D_)/1024, 256, 0, stream>>>(
      fparts, b2, xout, xout, BT_*D_, D_);
}

// Round 21
// 228.907 us; speedup vs baseline: 1.0863x; 1.0392x over previous
//
#include <hip/hip_runtime.h>
#include <hip/hip_bf16.h>
#include <cstdint>
#include <cstddef>
#include <math.h>

#define D_ 1024
#define H_ 16
#define HD_ 64
#define T_ 2048
#define B_ 2
#define FF_ 4096
#define BT_ (B_*T_)   // 4096 rows
#define NT_ 32        // T_/64 kv tiles

typedef unsigned short u16;
typedef __attribute__((ext_vector_type(8))) __bf16 bf16x8;
typedef __attribute__((ext_vector_type(8))) u16 u16x8;
typedef __attribute__((ext_vector_type(4))) float f32x4;

__device__ __forceinline__ u16 f2bf(float f) {
  unsigned u = __builtin_bit_cast(unsigned, f);
  u += 0x7FFFu + ((u >> 16) & 1u);
  return (u16)(u >> 16);
}

__device__ __forceinline__ float bf2f(u16 u) {
  return __builtin_bit_cast(float, ((unsigned)u) << 16);
}

__device__ __forceinline__ unsigned cvt_pk_bf16(float a, float b) {
  unsigned r;
  asm("v_cvt_pk_bf16_f32 %0, %1, %2" : "=v"(r) : "v"(a), "v"(b));
  return r;
}

__device__ __forceinline__ void gload16(const void* g, void* l) {
  __builtin_amdgcn_global_load_lds((__attribute__((address_space(1))) void*)g,
                                   (__attribute__((address_space(3))) void*)l, 16, 0, 0);
}

// ---------------- fused prep: transpose+cast ALL weights AND LayerNorm1 (1 launch)
__global__ __launch_bounds__(256) void prep_all(
    const float* __restrict__ wq, const float* __restrict__ wk,
    const float* __restrict__ wv, const float* __restrict__ w_proj,
    const float* __restrict__ w1, const float* __restrict__ w2,
    u16* __restrict__ wqkv_t, u16* __restrict__ wproj_t,
    u16* __restrict__ w1t, u16* __restrict__ w2t,
    const float* __restrict__ x, const float* __restrict__ ln1_g,
    const float* __restrict__ ln1_b, u16* __restrict__ hbuf) {
  __shared__ float tile[32][33];
  __shared__ float ss[4], qs[4];
  const int bid = blockIdx.x;
  if (bid >= 12288) {
    const int row = bid - 12288;
    const int tid = threadIdx.y * 32 + threadIdx.x;
    const float4 v = ((const float4*)(x + (size_t)row * D_))[tid];
    float s = v.x + v.y + v.z + v.w;
    float sq = v.x*v.x + v.y*v.y + v.z*v.z + v.w*v.w;
    #pragma unroll
    for (int m = 1; m < 64; m <<= 1) { s += __shfl_xor(s, m); sq += __shfl_xor(sq, m); }
    if ((tid & 63) == 0) { ss[tid >> 6] = s; qs[tid >> 6] = sq; }
    __syncthreads();
    s  = ss[0] + ss[1] + ss[2] + ss[3];
    sq = qs[0] + qs[1] + qs[2] + qs[3];
    const float mean = s * (1.f / D_);
    const float var  = sq * (1.f / D_) - mean * mean;
    const float rstd = rsqrtf(var + 1e-5f);
    const float4 gv = ((const float4*)ln1_g)[tid];
    const float4 bv = ((const float4*)ln1_b)[tid];
    u16 o[4];
    o[0] = f2bf((v.x - mean) * rstd * gv.x + bv.x);
    o[1] = f2bf((v.y - mean) * rstd * gv.y + bv.y);
    o[2] = f2bf((v.z - mean) * rstd * gv.z + bv.z);
    o[3] = f2bf((v.w - mean) * rstd * gv.w + bv.w);
    *(ushort4*)(hbuf + (size_t)row * D_ + tid * 4) = *(ushort4*)o;
    return;
  }
  const float* in; u16* out; int R, C, tx, ty;
  if (bid < 3072) {
    const int w = bid >> 10, rem = bid & 1023;
    const int z = rem >> 6, t = rem & 63;
    tx = t & 1; ty = t >> 1;
    R = D_; C = HD_;
    in  = (w == 0 ? wq : w == 1 ? wk : wv) + (size_t)z * R * C;
    out = wqkv_t + (size_t)w * D_ * D_ + (size_t)z * C * R;
  } else if (bid < 4096) {
    const int t = bid - 3072;
    tx = t & 31; ty = t >> 5;
    R = D_; C = D_; in = w_proj; out = wproj_t;
  } else if (bid < 8192) {
    const int t = bid - 4096;
    tx = t & 127; ty = t >> 7;
    R = D_; C = FF_; in = w1; out = w1t;
  } else {
    const int t = bid - 8192;
    tx = t & 31; ty = t >> 5;
    R = FF_; C = D_; in = w2; out = w2t;
  }
  const int xx = tx * 32 + threadIdx.x;
  const int y0 = ty * 32 + threadIdx.y;
  #pragma unroll
  for (int j = 0; j < 32; j += 8)
    tile[threadIdx.y + j][threadIdx.x] = in[(size_t)(y0 + j) * C + xx];
  __syncthreads();
  const int orr = ty * 32 + threadIdx.x;
  const int oc0 = tx * 32 + threadIdx.y;
  #pragma unroll
  for (int j = 0; j < 32; j += 8)
    out[(size_t)(oc0 + j) * R + orr] = f2bf(tile[threadIdx.x][threadIdx.y + j]);
}

// ---------------- GEMM 128x128, BK=32, 4 waves, 32KB LDS -> 4 blocks/CU,
// counted-vmcnt stage-ahead + T1 XCD swizzle + conflict-free (row>>1)&3 XOR layout.
// PARTIAL: bf16 split-K partials (round-21: halves partial HBM traffic; partial-sum
// magnitudes O(0.3) so bf16 rounding ~0.001/partial, far under the 0.12 threshold).
template<int ACT, int BIAS, int OUTBF, int PARTIAL, int QKVE>
__global__ __launch_bounds__(256, 4) void gemm128(
    const u16* __restrict__ A, const u16* __restrict__ Bt,
    const float* __restrict__ bias, const float* resid,
    void* Cout, int M, int N, int K, int Kper) {
  __shared__ __attribute__((aligned(16))) u16 LA[2][128 * 32];
  __shared__ __attribute__((aligned(16))) u16 LB[2][128 * 32];

  const int tid = threadIdx.x;
  const int wid = tid >> 6, lane = tid & 63;
  const int wr = wid >> 1, wc = wid & 1;
  const int frow = lane & 15, hi = lane >> 4;

  const int gx = gridDim.x;
  const int nwg = gx * gridDim.y;
  const int orig = blockIdx.y * gx + blockIdx.x;
  const int cpx = nwg >> 3;
  const int swz = (orig & 7) * cpx + (orig >> 3);
  const int bm = (swz / gx) * 128, bn = (swz % gx) * 128;
  const int z = PARTIAL ? blockIdx.z : 0;
  const int koff = z * Kper;
  const int nt = Kper >> 5;

  const int srow = tid >> 2;
  const int gch  = (tid & 3) ^ ((srow >> 1) & 3);
  const u16* Ag0 = A + (size_t)(bm + srow) * K + koff + gch * 8;
  const u16* Ag1 = Ag0 + (size_t)64 * K;
  const u16* Bg0 = Bt + (size_t)(bn + srow) * K + koff + gch * 8;
  const u16* Bg1 = Bg0 + (size_t)64 * K;
  const int ldsA0 = (wid * 16) * 32, ldsA1 = (64 + wid * 16) * 32;

  f32x4 acc[4][4] = {};

  #define STAGE32(kt, db)                              \
    {                                                  \
      const int ko = (kt) * 32;                        \
      gload16(Ag0 + ko, &LA[db][ldsA0]);               \
      gload16(Ag1 + ko, &LA[db][ldsA1]);               \
      gload16(Bg0 + ko, &LB[db][ldsA0]);               \
      gload16(Bg1 + ko, &LB[db][ldsA1]);               \
    }

  STAGE32(0, 0);

  for (int t = 0; t < nt; ++t) {
    const int db = t & 1;
    if (t + 1 < nt) {
      STAGE32(t + 1, db ^ 1);
      asm volatile("s_waitcnt vmcnt(4)" ::: "memory");
    } else {
      asm volatile("s_waitcnt vmcnt(0)" ::: "memory");
    }
    __builtin_amdgcn_s_barrier();

    const u16* Ab = &LA[db][0];
    const u16* Bb = &LB[db][0];

    bf16x8 af[4], bfr[4];
    #pragma unroll
    for (int i = 0; i < 4; i++) {
      const int ra = wr * 64 + i * 16 + frow;
      af[i]  = *(const bf16x8*)(Ab + ra * 32 + ((hi ^ ((ra >> 1) & 3)) << 3));
      const int rb = wc * 64 + i * 16 + frow;
      bfr[i] = *(const bf16x8*)(Bb + rb * 32 + ((hi ^ ((rb >> 1) & 3)) << 3));
    }
    __builtin_amdgcn_s_setprio(1);
    #pragma unroll
    for (int mi = 0; mi < 4; mi++)
      #pragma unroll
      for (int ni = 0; ni < 4; ni++)
        acc[mi][ni] = __builtin_amdgcn_mfma_f32_16x16x32_bf16(af[mi], bfr[ni], acc[mi][ni], 0, 0, 0);
    __builtin_amdgcn_s_setprio(0);
    __builtin_amdgcn_s_barrier();
  }
  #undef STAGE32

  const int r0 = bm + wr * 64 + hi * 4;
  const int c0 = bn + wc * 64 + frow;
  #pragma unroll
  for (int mi = 0; mi < 4; mi++) {
    #pragma unroll
    for (int ni = 0; ni < 4; ni++) {
      #pragma unroll
      for (int r = 0; r < 4; r++) {
        float v = acc[mi][ni][r];
        const int rr = r0 + mi * 16 + r;
        const int cc = c0 + ni * 16;
        if (QKVE) {
          const int region = bn >> 10;            // 0=Q, 1=K, 2=V
          u16* qo = (u16*)Cout;
          u16* ko = qo + (size_t)4 * 1024 * 1024; // +8MB
          u16* vo = qo + (size_t)8 * 1024 * 1024; // +16MB
          const int c1 = cc & 1023;
          const int h = c1 >> 6, d = c1 & 63;
          const int bb2 = rr >> 11, t2 = rr & 2047;
          const int bh = bb2 * 16 + h;
          if (region == 0)
            qo[((size_t)bh * T_ + t2) * HD_ + d] = f2bf(v * 0.18033688011112042f);
          else if (region == 1)
            ko[((size_t)bh * T_ + t2) * HD_ + d] = f2bf(v);
          else
            vo[((size_t)bh * HD_ + d) * T_ + t2] = f2bf(v);
        } else if (PARTIAL) {
          ((u16*)Cout)[((size_t)z * M + rr) * N + cc] = f2bf(v);
        } else {
          if (BIAS) v += bias[cc];
          if (ACT == 1) {
            const float u = v * (0.79788456f + 0.03567740814f * v * v);
            const float e = exp2f(fminf(u * 2.885390082f, 80.f));
            v = v - v * __builtin_amdgcn_rcpf(1.0f + e);
          }
          if (resid) v += resid[(size_t)rr * N + cc];
          if (OUTBF) ((u16*)Cout)[(size_t)rr * N + cc] = f2bf(v);
          else       ((float*)Cout)[(size_t)rr * N + cc] = v;
        }
      }
    }
  }
}

// ---------------- split-K reduce (bf16 partials): out = sum(parts)+bias(+resid), fp32
template<int NPART>
__global__ __launch_bounds__(256) void reduce_parts(
    const u16* __restrict__ parts, const float* __restrict__ bias,
    const float* __restrict__ resid, float* __restrict__ out, int MN, int N) {
  const int i4 = (blockIdx.x * 256 + threadIdx.x) * 4;
  if (i4 >= MN) return;
  const ushort4 p0 = *(const ushort4*)(parts + i4);
  float4 s = make_float4(bf2f(p0.x), bf2f(p0.y), bf2f(p0.z), bf2f(p0.w));
  #pragma unroll
  for (int p = 1; p < NPART; p++) {
    const ushort4 t = *(const ushort4*)(parts + (size_t)p * MN + i4);
    s.x += bf2f(t.x); s.y += bf2f(t.y); s.z += bf2f(t.z); s.w += bf2f(t.w);
  }
  const float4 bv = *(const float4*)(bias + (i4 & (N - 1)));
  const float4 rv = *(const float4*)(resid + i4);
  s.x += bv.x + rv.x; s.y += bv.y + rv.y; s.z += bv.z + rv.z; s.w += bv.w + rv.w;
  *(float4*)(out + i4) = s;
}

// ---------------- proj reduce (bf16 partials, NPART=2) + bias + residual + LN2.
__global__ __launch_bounds__(256) void reduce2_ln(
    const u16* __restrict__ parts, const float* __restrict__ bias,
    const float* __restrict__ resid, const float* __restrict__ g,
    const float* __restrict__ bb, float* __restrict__ xout,
    u16* __restrict__ h2, int MN) {
  const int row = blockIdx.x, tid = threadIdx.x;
  const int i4 = row * D_ + tid * 4;
  const ushort4 p0 = *(const ushort4*)(parts + i4);
  const ushort4 p1 = *(const ushort4*)(parts + (size_t)MN + i4);
  float4 s = make_float4(bf2f(p0.x) + bf2f(p1.x), bf2f(p0.y) + bf2f(p1.y),
                         bf2f(p0.z) + bf2f(p1.z), bf2f(p0.w) + bf2f(p1.w));
  const float4 bv = *(const float4*)(bias + tid * 4);
  const float4 rv = *(const float4*)(resid + i4);
  s.x += bv.x + rv.x; s.y += bv.y + rv.y;
  s.z += bv.z + rv.z; s.w += bv.w + rv.w;
  *(float4*)(xout + i4) = s;
  float sm = s.x + s.y + s.z + s.w;
  float sq = s.x*s.x + s.y*s.y + s.z*s.z + s.w*s.w;
  #pragma unroll
  for (int m = 1; m < 64; m <<= 1) { sm += __shfl_xor(sm, m); sq += __shfl_xor(sq, m); }
  __shared__ float ss[4], qs[4];
  if ((tid & 63) == 0) { ss[tid >> 6] = sm; qs[tid >> 6] = sq; }
  __syncthreads();
  sm = ss[0] + ss[1] + ss[2] + ss[3];
  sq = qs[0] + qs[1] + qs[2] + qs[3];
  const float mean = sm * (1.f / D_);
  const float var  = sq * (1.f / D_) - mean * mean;
  const float rstd = rsqrtf(var + 1e-5f);
  const float4 gv = ((const float4*)g)[tid];
  const float4 b2v = ((const float4*)bb)[tid];
  u16 o[4];
  o[0] = f2bf((s.x - mean) * rstd * gv.x + b2v.x);
  o[1] = f2bf((s.y - mean) * rstd * gv.y + b2v.y);
  o[2] = f2bf((s.z - mean) * rstd * gv.z + b2v.z);
  o[3] = f2bf((s.w - mean) * rstd * gv.w + b2v.w);
  *(ushort4*)(h2 + (size_t)row * D_ + tid * 4) = *(ushort4*)o;
}

// ---------------- flash attention v9: 1024 blocks, ONE 64-row q-block each.
// Per-CU quadruple {31-g, 16+g, 15-g, g} sums to 66 tile-rounds -> balanced at
// 3-4 co-resident blocks/CU; XCD-bh L2 locality; v7 body.
__global__ __launch_bounds__(256, 2) void attn_fwd(
    const u16* __restrict__ q, const u16* __restrict__ k,
    const u16* __restrict__ vt, u16* __restrict__ out) {
  __shared__ __attribute__((aligned(16))) u16 Ps[4][16 * 64];   // 8KB
  __shared__ __attribute__((aligned(16))) u16 Kb[2][64 * 64];   // 16KB
  __shared__ __attribute__((aligned(16))) u16 Vb[2][64 * 64];   // 16KB

  const int bid = blockIdx.x;                // 1024 blocks
  const int xcd = bid & 7, j = bid >> 3;     // j = 0..127
  const int c   = j & 31, s = j >> 5;        // c: per-XCD cu index, s: slot 0..3
  const int bh  = xcd + 8 * (c >> 3);        // 4 bh per xcd -> 2MB K/V, L2-resident
  const int g   = c & 7;
  const int qb  = (s == 0) ? (31 - g) : (s == 1) ? (16 + g) : (s == 2) ? (15 - g) : g;
  const int b = bh >> 4, h = bh & 15;
  const int tid = threadIdx.x, wid = tid >> 6, lane = tid & 63;
  const u16* kh = k  + (size_t)bh * T_ * HD_;
  const u16* vh = vt + (size_t)bh * HD_ * T_;

  const int frow = lane & 15;
  const int hi   = lane >> 4;
  const int fk   = hi * 8;
  const int rowb = hi * 4;
  const int colb = frow;
  const int srow = tid >> 3;                 // staging row 0..31 (per 32-row pass)
  const int gch  = (tid & 7) ^ (srow & 7);   // pre-swizzled chunk

  u16x8 onebits = (u16x8)((u16)0x3F80);
  bf16x8 b_one = (frow == 0) ? __builtin_bit_cast(bf16x8, onebits) : (bf16x8){};

  u16* Pw = &Ps[wid][0];

  const int q0 = qb * 64;
  const int nkt = qb + 1;

  const u16* qrow = q + ((size_t)bh * T_ + q0 + wid * 16 + frow) * HD_;
  bf16x8 aq[2];
  aq[0] = *(const bf16x8*)(qrow + fk);
  aq[1] = *(const bf16x8*)(qrow + 32 + fk);

  float m2[4] = {-3e38f, -3e38f, -3e38f, -3e38f};
  f32x4 acc_l = {};
  f32x4 acc_o[4] = {};

  int cur = 0;
  #pragma unroll
  for (int p = 0; p < 2; p++) {
    gload16(kh + (size_t)(p * 32 + srow) * HD_ + gch * 8, &Kb[0][(p * 32 + wid * 8) * 64]);
    gload16(vh + (size_t)(p * 32 + srow) * T_ + gch * 8,  &Vb[0][(p * 32 + wid * 8) * 64]);
  }
  __syncthreads();

  for (int kt = 0; kt < nkt; ++kt) {
    if (kt + 1 < nkt) {
      const int nx = cur ^ 1, ktn = kt + 1;
      #pragma unroll
      for (int p = 0; p < 2; p++) {
        gload16(kh + (size_t)(ktn * 64 + p * 32 + srow) * HD_ + gch * 8,
                &Kb[nx][(p * 32 + wid * 8) * 64]);
        gload16(vh + (size_t)(p * 32 + srow) * T_ + ktn * 64 + gch * 8,
                &Vb[nx][(p * 32 + wid * 8) * 64]);
      }
    }

    const u16* Kc = &Kb[cur][0];
    const u16* Vc = &Vb[cur][0];

    // ---- QK^T (q pre-scaled by 0.125*log2e)
    float p2[4][4];
    __builtin_amdgcn_s_setprio(1);
    #pragma unroll
    for (int ni = 0; ni < 4; ni++) {
      f32x4 s2 = {};
      #pragma unroll
      for (int ks = 0; ks < 2; ks++) {
        const int row = ni * 16 + frow;
        const int ch  = ks * 4 + hi;
        bf16x8 bk = *(const bf16x8*)(Kc + row * 64 + ((ch ^ (row & 7)) << 3));
        s2 = __builtin_amdgcn_mfma_f32_16x16x32_bf16(aq[ks], bk, s2, 0, 0, 0);
      }
      #pragma unroll
      for (int r = 0; r < 4; r++) p2[ni][r] = s2[r];
    }
    __builtin_amdgcn_s_setprio(0);

    if (kt == nkt - 1) {  // diagonal tile: mask cols > row
      #pragma unroll
      for (int ni = 0; ni < 4; ni++)
        #pragma unroll
        for (int r = 0; r < 4; r++) {
          const bool msk = (ni * 16 + colb) > (wid * 16 + rowb + r);
          if (msk) p2[ni][r] = -3e38f;
        }
    }

    // ---- lazy row max: local check, shuffles only on rescale events
    float lmax[4];
    #pragma unroll
    for (int r = 0; r < 4; r++)
      lmax[r] = fmaxf(fmaxf(p2[0][r], p2[1][r]), fmaxf(p2[2][r], p2[3][r]));
    int ok = 1;
    #pragma unroll
    for (int r = 0; r < 4; r++) ok &= (lmax[r] <= m2[r] + 8.0f);
    if (!__all(ok)) {
      #pragma unroll
      for (int r = 0; r < 4; r++) {
        float rm = lmax[r];
        rm = fmaxf(rm, __shfl_xor(rm, 1));
        rm = fmaxf(rm, __shfl_xor(rm, 2));
        rm = fmaxf(rm, __shfl_xor(rm, 4));
        rm = fmaxf(rm, __shfl_xor(rm, 8));
        const float mnew = fmaxf(m2[r], rm);
        const float corr = exp2f(m2[r] - mnew);
        m2[r] = mnew;
        acc_l[r] *= corr;
        #pragma unroll
        for (int ni = 0; ni < 4; ni++) acc_o[ni][r] *= corr;
      }
    }
    #pragma unroll
    for (int ni = 0; ni < 4; ni++)
      #pragma unroll
      for (int r = 0; r < 4; r++) p2[ni][r] = exp2f(p2[ni][r] - m2[r]);

    // ---- P -> per-wave swizzled LDS (cvt_pk), reload as A-frag
    #pragma unroll
    for (int ni = 0; ni < 4; ni++) {
      #pragma unroll
      for (int r = 0; r < 4; r += 2) {
        const unsigned pk = cvt_pk_bf16(p2[ni][r], p2[ni][r + 1]);
        const int lr0 = rowb + r, lr1 = rowb + r + 1;
        const int ch = ni * 2 + (colb >> 3);
        Pw[lr0 * 64 + ((ch ^ (lr0 & 7)) << 3) + (colb & 7)] = (u16)pk;
        Pw[lr1 * 64 + ((ch ^ (lr1 & 7)) << 3) + (colb & 7)] = (u16)(pk >> 16);
      }
    }
    bf16x8 ap[2];
    {
      const int c0 = (0 * 4 + hi) ^ (frow & 7);
      const int c1 = (1 * 4 + hi) ^ (frow & 7);
      ap[0] = *(const bf16x8*)(Pw + frow * 64 + (c0 << 3));
      ap[1] = *(const bf16x8*)(Pw + frow * 64 + (c1 << 3));
    }

    // ---- PV (+ ones-column for l)
    __builtin_amdgcn_s_setprio(1);
    #pragma unroll
    for (int ks = 0; ks < 2; ks++)
      acc_l = __builtin_amdgcn_mfma_f32_16x16x32_bf16(ap[ks], b_one, acc_l, 0, 0, 0);
    #pragma unroll
    for (int ni = 0; ni < 4; ni++) {
      #pragma unroll
      for (int ks = 0; ks < 2; ks++) {
        const int row = ni * 16 + frow;
        const int ch  = ks * 4 + hi;
        bf16x8 bv = *(const bf16x8*)(Vc + row * 64 + ((ch ^ (row & 7)) << 3));
        acc_o[ni] = __builtin_amdgcn_mfma_f32_16x16x32_bf16(ap[ks], bv, acc_o[ni], 0, 0, 0);
      }
    }
    __builtin_amdgcn_s_setprio(0);

    __syncthreads();
    cur ^= 1;
  }

  float linv[4];
  #pragma unroll
  for (int r = 0; r < 4; r++) {
    const float lv = __shfl(acc_l[r], lane & 48);
    linv[r] = 1.0f / lv;
  }
  #pragma unroll
  for (int ni = 0; ni < 4; ni++)
    #pragma unroll
    for (int r = 0; r < 4; r++) {
      const float ov = acc_o[ni][r] * linv[r];
      const size_t row = (size_t)b * T_ + q0 + wid * 16 + rowb + r;
      out[row * D_ + h * HD_ + ni * 16 + colb] = f2bf(ov);
    }
}

extern "C" void kernel_launch(void* const* d_in, const int* in_sizes, int n_in,
                              void* d_out, int out_size, void* d_ws, size_t ws_size,
                              hipStream_t stream) {
  (void)in_sizes; (void)n_in; (void)out_size; (void)ws_size;
  const float* x      = (const float*)d_in[0];
  const float* wq     = (const float*)d_in[1];
  const float* wk     = (const float*)d_in[2];
  const float* wv     = (const float*)d_in[3];
  const float* w_proj = (const float*)d_in[4];
  const float* b_proj = (const float*)d_in[5];
  const float* ln1_g  = (const float*)d_in[6];
  const float* ln1_b  = (const float*)d_in[7];
  const float* ln2_g  = (const float*)d_in[8];
  const float* ln2_b  = (const float*)d_in[9];
  const float* w1     = (const float*)d_in[10];
  const float* b1     = (const float*)d_in[11];
  const float* w2     = (const float*)d_in[12];
  const float* b2     = (const float*)d_in[13];

  uint8_t* ws = (uint8_t*)d_ws;
  const size_t MB = 1024 * 1024;
  u16* wqkv_t = (u16*)(ws + 0);        // [3072,1024]
  u16* wproj_t = (u16*)(ws + 6 * MB);  // [1024,1024]
  u16* w1t  = (u16*)(ws + 8 * MB);     // [4096,1024]
  u16* w2t  = (u16*)(ws + 16 * MB);    // [1024,4096]
  u16* hbuf = (u16*)(ws + 24 * MB);    // [4096,1024]
  u16* qb   = (u16*)(ws + 56 * MB);    // [32,2048,64]  Q (scaled)
  u16* kb   = (u16*)(ws + 64 * MB);    // [32,2048,64]  K   (qb+8MB)
  u16* vtb  = (u16*)(ws + 72 * MB);    // [32,64,2048]  V^T (qb+16MB)
  u16* aout = (u16*)(ws + 80 * MB);    // [4096,1024]
  u16* h2   = (u16*)(ws + 88 * MB);    // [4096,1024]
  u16* ff1  = (u16*)(ws + 96 * MB);    // [4096,4096]
  u16* pparts = (u16*)(ws + 32 * MB);  // proj: 2 x [4096,1024] bf16 = 16 MB
  u16* fparts = (u16*)(ws + 32 * MB);  // ff2:  4 x [4096,1024] bf16 = 32 MB
  float* xout = (float*)d_out;

  prep_all<<<16384, dim3(32, 8), 0, stream>>>(
      wq, wk, wv, w_proj, w1, w2, wqkv_t, wproj_t, w1t, w2t,
      x, ln1_g, ln1_b, hbuf);

  // QKV GEMM with fused repack epilogue: writes q(scaled)/k/vt directly
  gemm128<0,0,0,0,1><<<dim3(3072/128, BT_/128), 256, 0, stream>>>(
      hbuf, wqkv_t, nullptr, nullptr, qb, BT_, 3072, D_, D_);

  attn_fwd<<<dim3(1024), 256, 0, stream>>>(qb, kb, vtb, aout);

  // proj: split-K=2 bf16 partials, then fused reduce + bias + x-residual + LN2
  gemm128<0,0,0,1,0><<<dim3(D_/128, BT_/128, 2), 256, 0, stream>>>(
      aout, wproj_t, nullptr, nullptr, pparts, BT_, D_, D_, D_/2);
  reduce2_ln<<<BT_, 256, 0, stream>>>(
      pparts, b_proj, x, ln2_g, ln2_b, xout, h2, BT_*D_);

  // FF1: [4096,1024] x [4096,1024]^T -> GELU -> bf16 [4096,4096]
  gemm128<1,1,1,0,0><<<dim3(FF_/128, BT_/128), 256, 0, stream>>>(
      h2, w1t, b1, nullptr, ff1, BT_, FF_, D_, D_);

  // FF2: split-K=4 bf16 partials + fused reduce (bias + xout residual) -> xout
  gemm128<0,0,0,1,0><<<dim3(D_/128, BT_/128, 4), 256, 0, stream>>>(
      ff1, w2t, nullptr, nullptr, fparts, BT_, D_, FF_, FF_/4);
  reduce_parts<4><<<(BT_*D_)/1024, 256, 0, stream>>>(
      fparts, b2, xout, xout, BT_*D_, D_);
}